// Round 2
// baseline (367.999 us; speedup 1.0000x reference)
//
#include <hip/hip_runtime.h>
#include <stdint.h>

// Problem constants (from reference): B=2, S=4096, D_MODEL=1024, H=16, d_k=64
// RADIUS = ceil(sqrt(4*0.28*ln(1e6))*2) = 8, window = 9 (positions s-8..s)
constexpr int S_LEN = 4096;
constexpr int DM    = 1024;
constexpr int RAD   = 8;
constexpr float INV2T = 1.7857142857142858f; // 1/(2*0.28)

constexpr int BM = 128, BN = 128, BK = 32;

typedef short s8v  __attribute__((ext_vector_type(8)));   // 8 bf16 (4 VGPRs) MFMA frag
typedef float f32x4 __attribute__((ext_vector_type(4)));  // MFMA accumulator

static __device__ __forceinline__ unsigned short f2bf(float f) {
  unsigned u = __builtin_bit_cast(unsigned, f);
  u = (u + 0x7fffu + ((u >> 16) & 1u)) >> 16;   // RNE (inputs finite)
  return (unsigned short)u;
}
static __device__ __forceinline__ float bf2f(unsigned short h) {
  unsigned u = ((unsigned)h) << 16;
  return __builtin_bit_cast(float, u);
}

// async global->LDS, 16B/lane. LDS dst is wave-uniform base + lane*16 (HW rule).
static __device__ __forceinline__ void gl_lds16(const void* gp, void* lp) {
  auto g = (const __attribute__((address_space(1))) void*)(uintptr_t)gp;
  auto l = (__attribute__((address_space(3))) void*)(uint32_t)(uintptr_t)lp;
  __builtin_amdgcn_global_load_lds(g, l, 16, 0, 0);
}

// ---------------- cast x (fp32) -> bf16 hi + bf16 lo residual ----------------
__global__ __launch_bounds__(256) void sda_cast_split_kernel(const float* __restrict__ X,
                                                             unsigned short* __restrict__ Hi,
                                                             unsigned short* __restrict__ Lo) {
  int i = blockIdx.x * 256 + threadIdx.x;
  const float4* x4 = (const float4*)X;
  float4 a = x4[2 * i], b = x4[2 * i + 1];
  float f[8] = {a.x, a.y, a.z, a.w, b.x, b.y, b.z, b.w};
  union { unsigned short u[8]; uint4 v; } oh, ol;
#pragma unroll
  for (int j = 0; j < 8; ++j) {
    unsigned short h = f2bf(f[j]);
    oh.u[j] = h;
    ol.u[j] = f2bf(f[j] - bf2f(h));   // x - hi exact in fp32; lo captures bits 9..16
  }
  ((uint4*)Hi)[i] = oh.v;
  ((uint4*)Lo)[i] = ol.v;
}

// ---------------- W (K x N fp32) -> W^T (N x K bf16), optional lo residual ----
__global__ __launch_bounds__(256) void sda_transcast_kernel(const float* __restrict__ W,
                                                            unsigned short* __restrict__ Hi,
                                                            unsigned short* __restrict__ Lo) {
  __shared__ float t[32][33];
  int tx = threadIdx.x, ty = threadIdx.y;     // block (32,8)
  int n0 = blockIdx.x * 32, k0 = blockIdx.y * 32;
#pragma unroll
  for (int i = 0; i < 4; ++i)
    t[ty + 8 * i][tx] = W[(size_t)(k0 + ty + 8 * i) * DM + n0 + tx];
  __syncthreads();
#pragma unroll
  for (int i = 0; i < 4; ++i) {
    float f = t[tx][ty + 8 * i];
    unsigned short h = f2bf(f);
    size_t o = (size_t)(n0 + ty + 8 * i) * DM + k0 + tx;
    Hi[o] = h;
    if (Lo) Lo[o] = f2bf(f - bf2f(h));
  }
}

// ---------------- plain bf16 GEMM: C[M,N] = A * B, B given as B^T[N,K] --------
// m97 recipe: 128x128 tile, BK=32, 4 waves 2x2, 16x16x32 bf16 MFMA,
// global_load_lds width=16 staging, two-barrier K-loop.
template <bool OUTBF>
__global__ __launch_bounds__(256) void sda_gemm_bt_kernel(
    const unsigned short* __restrict__ A, const unsigned short* __restrict__ Bt,
    void* __restrict__ Cv) {
  constexpr int Kd = DM, Nd = DM;
  __shared__ __align__(16) unsigned short As[BM * BK];  // [m][k], 64B rows
  __shared__ __align__(16) unsigned short Bs[BN * BK];  // [n][k]

  int tid = threadIdx.x, wid = tid >> 6, lane = tid & 63;
  int m0 = blockIdx.y * BM, n0 = blockIdx.x * BN;
  int srow = lane >> 2;          // staging row within 16 (lane/4)
  int schunk = (lane & 3) * 8;   // staging k-chunk (8 bf16 = 16B)
  int wm = (wid >> 1) * 64, wn = (wid & 1) * 64;
  int fm = lane & 15, fk = (lane >> 4) * 8;  // MFMA frag: m/n = lane&15, k = quad*8

  f32x4 acc[4][4] = {};

  for (int kt = 0; kt < Kd / BK; ++kt) {
    if (kt) __syncthreads();
    int kk = kt * BK;
    int r0 = wid * 32;
    gl_lds16(A  + (size_t)(m0 + r0 + srow)      * Kd + kk + schunk, &As[(r0)      * BK]);
    gl_lds16(A  + (size_t)(m0 + r0 + 16 + srow) * Kd + kk + schunk, &As[(r0 + 16) * BK]);
    gl_lds16(Bt + (size_t)(n0 + r0 + srow)      * Kd + kk + schunk, &Bs[(r0)      * BK]);
    gl_lds16(Bt + (size_t)(n0 + r0 + 16 + srow) * Kd + kk + schunk, &Bs[(r0 + 16) * BK]);
    __syncthreads();

    s8v af[4], bfr[4];
#pragma unroll
    for (int i = 0; i < 4; ++i)
      af[i] = *(const s8v*)&As[(wm + i * 16 + fm) * BK + fk];
#pragma unroll
    for (int j = 0; j < 4; ++j)
      bfr[j] = *(const s8v*)&Bs[(wn + j * 16 + fm) * BK + fk];
#pragma unroll
    for (int i = 0; i < 4; ++i)
#pragma unroll
      for (int j = 0; j < 4; ++j)
        acc[i][j] = __builtin_amdgcn_mfma_f32_16x16x32_bf16(af[i], bfr[j], acc[i][j], 0, 0, 0);
  }

  // C/D layout (m89-verified): col = lane&15, row = (lane>>4)*4 + reg
  int rr = (lane >> 4) * 4, cc = lane & 15;
#pragma unroll
  for (int i = 0; i < 4; ++i)
#pragma unroll
    for (int j = 0; j < 4; ++j) {
      size_t base = (size_t)(m0 + wm + i * 16 + rr) * Nd + (n0 + wn + j * 16 + cc);
#pragma unroll
      for (int r = 0; r < 4; ++r) {
        float v = acc[i][j][r];
        if constexpr (OUTBF) ((unsigned short*)Cv)[base + (size_t)r * Nd] = f2bf(v);
        else                 ((float*)Cv)[base + (size_t)r * Nd] = v;
      }
    }
}

// ---------------- split-precision GEMM: C = (Ah+Al)(Bh+Bl) ~ AhBh+AhBl+AlBh ---
// fp32 output. Used for Q and K so softmax logits see ~fp32-accurate inputs.
__global__ __launch_bounds__(256) void sda_gemm_bt_split_kernel(
    const unsigned short* __restrict__ Ah, const unsigned short* __restrict__ Al,
    const unsigned short* __restrict__ Bh0, const unsigned short* __restrict__ Bl0,
    const unsigned short* __restrict__ Bh1, const unsigned short* __restrict__ Bl1,
    float* __restrict__ C0, float* __restrict__ C1) {
  constexpr int Kd = DM, Nd = DM;
  __shared__ __align__(16) unsigned short Ahs[BM * BK], Als[BM * BK];
  __shared__ __align__(16) unsigned short Bhs[BN * BK], Bls[BN * BK];
  const unsigned short* Bh = blockIdx.z == 0 ? Bh0 : Bh1;
  const unsigned short* Bl = blockIdx.z == 0 ? Bl0 : Bl1;
  float* C = blockIdx.z == 0 ? C0 : C1;

  int tid = threadIdx.x, wid = tid >> 6, lane = tid & 63;
  int m0 = blockIdx.y * BM, n0 = blockIdx.x * BN;
  int srow = lane >> 2, schunk = (lane & 3) * 8;
  int wm = (wid >> 1) * 64, wn = (wid & 1) * 64;
  int fm = lane & 15, fk = (lane >> 4) * 8;

  f32x4 acc[4][4] = {};

  for (int kt = 0; kt < Kd / BK; ++kt) {
    if (kt) __syncthreads();
    int kk = kt * BK;
    int r0 = wid * 32;
    size_t ga0 = (size_t)(m0 + r0 + srow) * Kd + kk + schunk;
    size_t ga1 = (size_t)(m0 + r0 + 16 + srow) * Kd + kk + schunk;
    size_t gb0 = (size_t)(n0 + r0 + srow) * Kd + kk + schunk;
    size_t gb1 = (size_t)(n0 + r0 + 16 + srow) * Kd + kk + schunk;
    gl_lds16(Ah + ga0, &Ahs[(r0)      * BK]);
    gl_lds16(Ah + ga1, &Ahs[(r0 + 16) * BK]);
    gl_lds16(Al + ga0, &Als[(r0)      * BK]);
    gl_lds16(Al + ga1, &Als[(r0 + 16) * BK]);
    gl_lds16(Bh + gb0, &Bhs[(r0)      * BK]);
    gl_lds16(Bh + gb1, &Bhs[(r0 + 16) * BK]);
    gl_lds16(Bl + gb0, &Bls[(r0)      * BK]);
    gl_lds16(Bl + gb1, &Bls[(r0 + 16) * BK]);
    __syncthreads();

    s8v ah[4], al[4], bh[4], bl[4];
#pragma unroll
    for (int i = 0; i < 4; ++i) {
      ah[i] = *(const s8v*)&Ahs[(wm + i * 16 + fm) * BK + fk];
      al[i] = *(const s8v*)&Als[(wm + i * 16 + fm) * BK + fk];
    }
#pragma unroll
    for (int j = 0; j < 4; ++j) {
      bh[j] = *(const s8v*)&Bhs[(wn + j * 16 + fm) * BK + fk];
      bl[j] = *(const s8v*)&Bls[(wn + j * 16 + fm) * BK + fk];
    }
#pragma unroll
    for (int i = 0; i < 4; ++i)
#pragma unroll
      for (int j = 0; j < 4; ++j) {
        acc[i][j] = __builtin_amdgcn_mfma_f32_16x16x32_bf16(ah[i], bh[j], acc[i][j], 0, 0, 0);
        acc[i][j] = __builtin_amdgcn_mfma_f32_16x16x32_bf16(ah[i], bl[j], acc[i][j], 0, 0, 0);
        acc[i][j] = __builtin_amdgcn_mfma_f32_16x16x32_bf16(al[i], bh[j], acc[i][j], 0, 0, 0);
      }
  }

  int rr = (lane >> 4) * 4, cc = lane & 15;
#pragma unroll
  for (int i = 0; i < 4; ++i)
#pragma unroll
    for (int j = 0; j < 4; ++j) {
      size_t base = (size_t)(m0 + wm + i * 16 + rr) * Nd + (n0 + wn + j * 16 + cc);
#pragma unroll
      for (int r = 0; r < 4; ++r)
        C[base + (size_t)r * Nd] = acc[i][j][r];
    }
}

// ---------------- windowed attention (Q,K fp32; V bf16) ----------------
// Grid (S/64, B*H). Block = 256 = 4 waves; wave handles 16 positions, lane = d.
__global__ __launch_bounds__(256) void sda_attn_kernel(
    const float* __restrict__ Q, const float* __restrict__ K,
    const unsigned short* __restrict__ V, unsigned short* __restrict__ O) {
  __shared__ __align__(16) float ks[72 * 64];
  __shared__ __align__(16) unsigned short vs[72 * 64];
  int bh = blockIdx.y, b = bh >> 4, h = bh & 15;
  int s0 = blockIdx.x * 64;
  int tid = threadIdx.x;
  size_t headoff = (size_t)b * S_LEN * DM + h * 64;

  for (int idx = tid; idx < 72 * 16; idx += 256) {    // K: 72 rows x 16 chunks of 4 floats
    int row = idx >> 4, ch = (idx & 15) * 4;
    int pos = s0 - RAD + row;
    float4 kv = make_float4(0.f, 0.f, 0.f, 0.f);
    if (pos >= 0) kv = *(const float4*)(K + headoff + (size_t)pos * DM + ch);
    *(float4*)&ks[row * 64 + ch] = kv;
  }
  for (int idx = tid; idx < 72 * 8; idx += 256) {     // V: 72 rows x 8 chunks of 16B
    int row = idx >> 3, ch = (idx & 7) * 8;
    int pos = s0 - RAD + row;
    uint4 vv = make_uint4(0, 0, 0, 0);
    if (pos >= 0) vv = *(const uint4*)(V + headoff + (size_t)pos * DM + ch);
    *(uint4*)&vs[row * 64 + ch] = vv;
  }
  __syncthreads();

  int w = tid >> 6, lane = tid & 63;
  for (int it = 0; it < 16; ++it) {
    int sl = w * 16 + it;
    int s = s0 + sl;
    float qd = Q[headoff + (size_t)s * DM + lane];
    float sc[9];
    float mx = -1e30f;
#pragma unroll
    for (int j = 0; j < 9; ++j) {
      float p = qd * ks[(sl + j) * 64 + lane];
      p += __shfl_xor(p, 1);
      p += __shfl_xor(p, 2);
      p += __shfl_xor(p, 4);
      p += __shfl_xor(p, 8);
      p += __shfl_xor(p, 16);
      p += __shfl_xor(p, 32);
      p *= INV2T;
      sc[j] = (s - RAD + j >= 0) ? p : -1e30f;        // wave-uniform mask
      mx = fmaxf(mx, sc[j]);
    }
    float se = 0.f, od = 0.f;
#pragma unroll
    for (int j = 0; j < 9; ++j) {
      float wj = __expf(sc[j] - mx);                  // 0 for masked
      se += wj;
      od += wj * bf2f(vs[(sl + j) * 64 + lane]);
    }
    O[headoff + (size_t)s * DM + lane] = f2bf(od / se);
  }
}

extern "C" void kernel_launch(void* const* d_in, const int* in_sizes, int n_in,
                              void* d_out, int out_size, void* d_ws, size_t ws_size,
                              hipStream_t stream) {
  (void)in_sizes; (void)n_in; (void)out_size; (void)ws_size;
  const float* x  = (const float*)d_in[0];
  const float* Wq = (const float*)d_in[1];
  const float* Wk = (const float*)d_in[2];
  const float* Wv = (const float*)d_in[3];
  const float* Wo = (const float*)d_in[4];

  char* ws = (char*)d_ws;
  const size_t MB = 1ull << 20;
  // Liveness-aware layout (108 MB total):
  unsigned short* xb_hi = (unsigned short*)(ws + 0);        // 16 MB [steps 1-4]
  unsigned short* xb_lo = (unsigned short*)(ws + 16 * MB);  // 16 MB [steps 1-3]
  unsigned short* WqTh  = (unsigned short*)(ws + 32 * MB);  // 2 MB each
  unsigned short* WkTh  = (unsigned short*)(ws + 34 * MB);
  unsigned short* WvTh  = (unsigned short*)(ws + 36 * MB);
  unsigned short* WoTh  = (unsigned short*)(ws + 38 * MB);
  unsigned short* WqTl  = (unsigned short*)(ws + 40 * MB);
  unsigned short* WkTl  = (unsigned short*)(ws + 42 * MB);
  float*          Qf    = (float*)(ws + 44 * MB);           // 32 MB
  float*          Kf    = (float*)(ws + 76 * MB);           // 32 MB
  unsigned short* Vb    = (unsigned short*)(ws + 16 * MB);  // alias xb_lo (dead after QK GEMM)
  unsigned short* Ab    = (unsigned short*)(ws + 0);        // alias xb_hi (dead after V GEMM)

  sda_cast_split_kernel<<<4096, 256, 0, stream>>>(x, xb_hi, xb_lo);
  dim3 tb(32, 8), tg(32, 32);
  sda_transcast_kernel<<<tg, tb, 0, stream>>>(Wq, WqTh, WqTl);
  sda_transcast_kernel<<<tg, tb, 0, stream>>>(Wk, WkTh, WkTl);
  sda_transcast_kernel<<<tg, tb, 0, stream>>>(Wv, WvTh, nullptr);
  sda_transcast_kernel<<<tg, tb, 0, stream>>>(Wo, WoTh, nullptr);

  // Q,K: split-precision (fp32-accurate into softmax). M=8192 -> 8x64 tiles, z = {Q,K}.
  sda_gemm_bt_split_kernel<<<dim3(8, 64, 2), 256, 0, stream>>>(
      xb_hi, xb_lo, WqTh, WqTl, WkTh, WkTl, Qf, Kf);
  // V: plain bf16.
  sda_gemm_bt_kernel<true><<<dim3(8, 64, 1), 256, 0, stream>>>(xb_hi, WvTh, Vb);
  sda_attn_kernel<<<dim3(64, 32), 256, 0, stream>>>(Qf, Kf, Vb, Ab);
  sda_gemm_bt_kernel<false><<<dim3(8, 64, 1), 256, 0, stream>>>(Ab, WoTh, d_out);
}

// Round 3
// 283.046 us; speedup vs baseline: 1.3001x; 1.3001x over previous
//
#include <hip/hip_runtime.h>
#include <stdint.h>

// Problem constants (from reference): B=2, S=4096, D_MODEL=1024, H=16, d_k=64
// RADIUS = ceil(sqrt(4*0.28*ln(1e6))*2) = 8, window = 9 (positions s-8..s)
constexpr int S_LEN = 4096;
constexpr int DM    = 1024;
constexpr int RAD   = 8;
constexpr float INV2T = 1.7857142857142858f; // 1/(2*0.28)

constexpr int BM = 128, BN = 128, BK = 32;

// fp16 path: 11 mantissa bits (8x less rounding than bf16) at the SAME MFMA
// rate (m64: 1955 TF). Single-pass GEMMs replace round-2's 3-pass bf16 split.
typedef _Float16 h8v __attribute__((ext_vector_type(8)));  // 8 f16 (4 VGPRs) MFMA frag
typedef float f32x4  __attribute__((ext_vector_type(4)));  // MFMA accumulator

// async global->LDS, 16B/lane. LDS dst is wave-uniform base + lane*16 (HW rule).
static __device__ __forceinline__ void gl_lds16(const void* gp, void* lp) {
  auto g = (const __attribute__((address_space(1))) void*)(uintptr_t)gp;
  auto l = (__attribute__((address_space(3))) void*)(uint32_t)(uintptr_t)lp;
  __builtin_amdgcn_global_load_lds(g, l, 16, 0, 0);
}

// ---------------- cast x (fp32) -> fp16, 8 elems/thread ----------------
__global__ __launch_bounds__(256) void sda_cast_kernel(const float* __restrict__ X,
                                                       _Float16* __restrict__ Y) {
  int i = blockIdx.x * 256 + threadIdx.x;
  const float4* x4 = (const float4*)X;
  float4 a = x4[2 * i], b = x4[2 * i + 1];
  float f[8] = {a.x, a.y, a.z, a.w, b.x, b.y, b.z, b.w};
  union { _Float16 h[8]; uint4 v; } o;
#pragma unroll
  for (int j = 0; j < 8; ++j) o.h[j] = (_Float16)f[j];   // v_cvt_f16_f32, RNE
  ((uint4*)Y)[i] = o.v;
}

// ---------------- W (K x N fp32) -> W^T (N x K fp16), all 4 weights ----------
__global__ __launch_bounds__(256) void sda_transcast_kernel(
    const float* __restrict__ W0, const float* __restrict__ W1,
    const float* __restrict__ W2, const float* __restrict__ W3,
    _Float16* __restrict__ T0, _Float16* __restrict__ T1,
    _Float16* __restrict__ T2, _Float16* __restrict__ T3) {
  __shared__ float t[32][33];
  const float* W = blockIdx.z == 0 ? W0 : (blockIdx.z == 1 ? W1 : (blockIdx.z == 2 ? W2 : W3));
  _Float16*    T = blockIdx.z == 0 ? T0 : (blockIdx.z == 1 ? T1 : (blockIdx.z == 2 ? T2 : T3));
  int tx = threadIdx.x, ty = threadIdx.y;     // block (32,8)
  int n0 = blockIdx.x * 32, k0 = blockIdx.y * 32;
#pragma unroll
  for (int i = 0; i < 4; ++i)
    t[ty + 8 * i][tx] = W[(size_t)(k0 + ty + 8 * i) * DM + n0 + tx];
  __syncthreads();
#pragma unroll
  for (int i = 0; i < 4; ++i)
    T[(size_t)(n0 + ty + 8 * i) * DM + k0 + tx] = (_Float16)t[tx][ty + 8 * i];
}

// ---------------- fp16 GEMM: C[M,N] = A * B, B given as B^T[N,K] ------------
// m97 recipe: 128x128 tile, BK=32, 4 waves 2x2, 16x16x32 f16 MFMA,
// global_load_lds width=16 staging, two-barrier K-loop. z selects B/C (QKV fusion).
template <bool OUTF16>
__global__ __launch_bounds__(256) void sda_gemm_bt_kernel(
    const _Float16* __restrict__ A,
    const _Float16* __restrict__ B0, const _Float16* __restrict__ B1,
    const _Float16* __restrict__ B2,
    void* __restrict__ C0, void* __restrict__ C1, void* __restrict__ C2) {
  constexpr int Kd = DM, Nd = DM;
  __shared__ __align__(16) _Float16 As[BM * BK];  // [m][k], 64B rows
  __shared__ __align__(16) _Float16 Bs[BN * BK];  // [n][k]
  const _Float16* Bt = blockIdx.z == 0 ? B0 : (blockIdx.z == 1 ? B1 : B2);
  void* Cv = blockIdx.z == 0 ? C0 : (blockIdx.z == 1 ? C1 : C2);

  int tid = threadIdx.x, wid = tid >> 6, lane = tid & 63;
  int m0 = blockIdx.y * BM, n0 = blockIdx.x * BN;
  int srow = lane >> 2;          // staging row within 16 (lane/4)
  int schunk = (lane & 3) * 8;   // staging k-chunk (8 f16 = 16B)
  int wm = (wid >> 1) * 64, wn = (wid & 1) * 64;
  int fm = lane & 15, fk = (lane >> 4) * 8;  // MFMA frag: m/n = lane&15, k = quad*8

  f32x4 acc[4][4] = {};

  for (int kt = 0; kt < Kd / BK; ++kt) {
    if (kt) __syncthreads();                 // protect LDS before overwrite
    int kk = kt * BK;
    int r0 = wid * 32;                       // each wave stages 32 rows of A and of B
    gl_lds16(A  + (size_t)(m0 + r0 + srow)      * Kd + kk + schunk, &As[(r0)      * BK]);
    gl_lds16(A  + (size_t)(m0 + r0 + 16 + srow) * Kd + kk + schunk, &As[(r0 + 16) * BK]);
    gl_lds16(Bt + (size_t)(n0 + r0 + srow)      * Kd + kk + schunk, &Bs[(r0)      * BK]);
    gl_lds16(Bt + (size_t)(n0 + r0 + 16 + srow) * Kd + kk + schunk, &Bs[(r0 + 16) * BK]);
    __syncthreads();                         // waits vmcnt(0): staging complete

    h8v af[4], bfr[4];
#pragma unroll
    for (int i = 0; i < 4; ++i)
      af[i] = *(const h8v*)&As[(wm + i * 16 + fm) * BK + fk];
#pragma unroll
    for (int j = 0; j < 4; ++j)
      bfr[j] = *(const h8v*)&Bs[(wn + j * 16 + fm) * BK + fk];
#pragma unroll
    for (int i = 0; i < 4; ++i)
#pragma unroll
      for (int j = 0; j < 4; ++j)
        acc[i][j] = __builtin_amdgcn_mfma_f32_16x16x32_f16(af[i], bfr[j], acc[i][j], 0, 0, 0);
  }

  // C/D layout (m89-verified, dtype-independent): col = lane&15, row = (lane>>4)*4 + reg
  int rr = (lane >> 4) * 4, cc = lane & 15;
#pragma unroll
  for (int i = 0; i < 4; ++i)
#pragma unroll
    for (int j = 0; j < 4; ++j) {
      size_t base = (size_t)(m0 + wm + i * 16 + rr) * Nd + (n0 + wn + j * 16 + cc);
#pragma unroll
      for (int r = 0; r < 4; ++r) {
        float v = acc[i][j][r];
        if constexpr (OUTF16) ((_Float16*)Cv)[base + (size_t)r * Nd] = (_Float16)v;
        else                  ((float*)Cv)[base + (size_t)r * Nd] = v;
      }
    }
}

// ---------------- windowed attention (Q,K,V fp16; fp32 math) ----------------
// Grid (S/64, B*H). Block = 256 = 4 waves; wave handles 16 positions, lane = d.
// K/V rows [s0-8, s0+63] staged in LDS once per block.
__global__ __launch_bounds__(256) void sda_attn_kernel(
    const _Float16* __restrict__ Q, const _Float16* __restrict__ K,
    const _Float16* __restrict__ V, _Float16* __restrict__ O) {
  __shared__ __align__(16) _Float16 ks[72 * 64];
  __shared__ __align__(16) _Float16 vs[72 * 64];
  int bh = blockIdx.y, b = bh >> 4, h = bh & 15;
  int s0 = blockIdx.x * 64;
  int tid = threadIdx.x;
  size_t headoff = (size_t)b * S_LEN * DM + h * 64;

  for (int idx = tid; idx < 72 * 8; idx += 256) {     // 72 rows x 8 chunks of 16B
    int row = idx >> 3, ch = (idx & 7) * 8;
    int pos = s0 - RAD + row;
    uint4 kv = make_uint4(0, 0, 0, 0), vv = make_uint4(0, 0, 0, 0);
    if (pos >= 0) {
      size_t off = headoff + (size_t)pos * DM + ch;
      kv = *(const uint4*)(K + off);
      vv = *(const uint4*)(V + off);
    }
    *(uint4*)&ks[row * 64 + ch] = kv;                 // zero-fill invalid rows
    *(uint4*)&vs[row * 64 + ch] = vv;
  }
  __syncthreads();

  int w = tid >> 6, lane = tid & 63;
  for (int it = 0; it < 16; ++it) {
    int sl = w * 16 + it;
    int s = s0 + sl;
    float qd = (float)Q[headoff + (size_t)s * DM + lane];
    float sc[9];
    float mx = -1e30f;
#pragma unroll
    for (int j = 0; j < 9; ++j) {
      float p = qd * (float)ks[(sl + j) * 64 + lane];
      p += __shfl_xor(p, 1);
      p += __shfl_xor(p, 2);
      p += __shfl_xor(p, 4);
      p += __shfl_xor(p, 8);
      p += __shfl_xor(p, 16);
      p += __shfl_xor(p, 32);
      p *= INV2T;
      sc[j] = (s - RAD + j >= 0) ? p : -1e30f;        // wave-uniform mask
      mx = fmaxf(mx, sc[j]);
    }
    float se = 0.f, od = 0.f;
#pragma unroll
    for (int j = 0; j < 9; ++j) {
      float wj = __expf(sc[j] - mx);                  // 0 for masked
      se += wj;
      od += wj * (float)vs[(sl + j) * 64 + lane];
    }
    O[headoff + (size_t)s * DM + lane] = (_Float16)(od / se);
  }
}

extern "C" void kernel_launch(void* const* d_in, const int* in_sizes, int n_in,
                              void* d_out, int out_size, void* d_ws, size_t ws_size,
                              hipStream_t stream) {
  (void)in_sizes; (void)n_in; (void)out_size; (void)ws_size;
  const float* x  = (const float*)d_in[0];
  const float* Wq = (const float*)d_in[1];
  const float* Wk = (const float*)d_in[2];
  const float* Wv = (const float*)d_in[3];
  const float* Wo = (const float*)d_in[4];

  char* ws = (char*)d_ws;
  const size_t MB = 1ull << 20;
  _Float16* xh  = (_Float16*)(ws + 0);        // 16 MB
  _Float16* WqT = (_Float16*)(ws + 16 * MB);  // 2 MB each
  _Float16* WkT = (_Float16*)(ws + 18 * MB);
  _Float16* WvT = (_Float16*)(ws + 20 * MB);
  _Float16* WoT = (_Float16*)(ws + 22 * MB);
  _Float16* Qh  = (_Float16*)(ws + 24 * MB);  // 16 MB each
  _Float16* Kh  = (_Float16*)(ws + 40 * MB);
  _Float16* Vh  = (_Float16*)(ws + 56 * MB);
  _Float16* Ah  = (_Float16*)(ws + 72 * MB);  // total 88 MB

  sda_cast_kernel<<<4096, 256, 0, stream>>>(x, xh);
  sda_transcast_kernel<<<dim3(32, 32, 4), dim3(32, 8), 0, stream>>>(
      Wq, Wk, Wv, Wo, WqT, WkT, WvT, WoT);

  // QKV: one launch, z selects weight/output (M=8192, N=1024 -> 8x64 tiles)
  sda_gemm_bt_kernel<true><<<dim3(8, 64, 3), 256, 0, stream>>>(
      xh, WqT, WkT, WvT, Qh, Kh, Vh);
  sda_attn_kernel<<<dim3(64, 32), 256, 0, stream>>>(Qh, Kh, Vh, Ah);
  sda_gemm_bt_kernel<false><<<dim3(8, 64, 1), 256, 0, stream>>>(
      Ah, WoT, WoT, WoT, d_out, d_out, d_out);
}

// Round 4
// 214.583 us; speedup vs baseline: 1.7150x; 1.3191x over previous
//
#include <hip/hip_runtime.h>
#include <stdint.h>

// Problem constants (from reference): B=2, S=4096, D_MODEL=1024, H=16, d_k=64
// RADIUS = ceil(sqrt(4*0.28*ln(1e6))*2) = 8, window = 9 (positions s-8..s)
constexpr int S_LEN = 4096;
constexpr int DM    = 1024;
constexpr int RAD   = 8;
constexpr float INV2T = 1.7857142857142858f; // 1/(2*0.28)

constexpr int BM = 128, BN = 128, BK = 32;

// fp16 path: 11 mantissa bits (8x less rounding than bf16) at the SAME MFMA rate.
typedef _Float16 h8v __attribute__((ext_vector_type(8)));  // 8 f16 (4 VGPRs) MFMA frag
typedef float f32x4  __attribute__((ext_vector_type(4)));  // MFMA accumulator

// async global->LDS, 16B/lane. LDS dst is wave-uniform base + lane*16 (HW rule).
static __device__ __forceinline__ void gl_lds16(const void* gp, void* lp) {
  auto g = (const __attribute__((address_space(1))) void*)(uintptr_t)gp;
  auto l = (__attribute__((address_space(3))) void*)(uint32_t)(uintptr_t)lp;
  __builtin_amdgcn_global_load_lds(g, l, 16, 0, 0);
}

// ---------------- cast x (fp32) -> fp16, 8 elems/thread ----------------
__global__ __launch_bounds__(256) void sda_cast_kernel(const float* __restrict__ X,
                                                       _Float16* __restrict__ Y) {
  int i = blockIdx.x * 256 + threadIdx.x;
  const float4* x4 = (const float4*)X;
  float4 a = x4[2 * i], b = x4[2 * i + 1];
  float f[8] = {a.x, a.y, a.z, a.w, b.x, b.y, b.z, b.w};
  union { _Float16 h[8]; uint4 v; } o;
#pragma unroll
  for (int j = 0; j < 8; ++j) o.h[j] = (_Float16)f[j];   // v_cvt_f16_f32, RNE
  ((uint4*)Y)[i] = o.v;
}

// ---------------- W (K x N fp32) -> W^T (N x K fp16), all 4 weights ----------
__global__ __launch_bounds__(256) void sda_transcast_kernel(
    const float* __restrict__ W0, const float* __restrict__ W1,
    const float* __restrict__ W2, const float* __restrict__ W3,
    _Float16* __restrict__ T0, _Float16* __restrict__ T1,
    _Float16* __restrict__ T2, _Float16* __restrict__ T3) {
  __shared__ float t[32][33];
  const float* W = blockIdx.z == 0 ? W0 : (blockIdx.z == 1 ? W1 : (blockIdx.z == 2 ? W2 : W3));
  _Float16*    T = blockIdx.z == 0 ? T0 : (blockIdx.z == 1 ? T1 : (blockIdx.z == 2 ? T2 : T3));
  int tx = threadIdx.x, ty = threadIdx.y;     // block (32,8)
  int n0 = blockIdx.x * 32, k0 = blockIdx.y * 32;
#pragma unroll
  for (int i = 0; i < 4; ++i)
    t[ty + 8 * i][tx] = W[(size_t)(k0 + ty + 8 * i) * DM + n0 + tx];
  __syncthreads();
#pragma unroll
  for (int i = 0; i < 4; ++i)
    T[(size_t)(n0 + ty + 8 * i) * DM + k0 + tx] = (_Float16)t[tx][ty + 8 * i];
}

// ---------------- fp16 GEMM: C[M,N] = A * B, B given as B^T[N,K] ------------
// m97 recipe: 128x128 tile, BK=32, 4 waves 2x2, 16x16x32 f16 MFMA,
// global_load_lds width=16 staging, two-barrier K-loop. z selects B/C (QKV fusion).
template <bool OUTF16>
__global__ __launch_bounds__(256) void sda_gemm_bt_kernel(
    const _Float16* __restrict__ A,
    const _Float16* __restrict__ B0, const _Float16* __restrict__ B1,
    const _Float16* __restrict__ B2,
    void* __restrict__ C0, void* __restrict__ C1, void* __restrict__ C2) {
  constexpr int Kd = DM, Nd = DM;
  __shared__ __align__(16) _Float16 As[BM * BK];  // [m][k], 64B rows
  __shared__ __align__(16) _Float16 Bs[BN * BK];  // [n][k]
  const _Float16* Bt = blockIdx.z == 0 ? B0 : (blockIdx.z == 1 ? B1 : B2);
  void* Cv = blockIdx.z == 0 ? C0 : (blockIdx.z == 1 ? C1 : C2);

  int tid = threadIdx.x, wid = tid >> 6, lane = tid & 63;
  int m0 = blockIdx.y * BM, n0 = blockIdx.x * BN;
  int srow = lane >> 2;          // staging row within 16 (lane/4)
  int schunk = (lane & 3) * 8;   // staging k-chunk (8 f16 = 16B)
  int wm = (wid >> 1) * 64, wn = (wid & 1) * 64;
  int fm = lane & 15, fk = (lane >> 4) * 8;  // MFMA frag: m/n = lane&15, k = quad*8

  f32x4 acc[4][4] = {};

  for (int kt = 0; kt < Kd / BK; ++kt) {
    if (kt) __syncthreads();                 // protect LDS before overwrite
    int kk = kt * BK;
    int r0 = wid * 32;                       // each wave stages 32 rows of A and of B
    gl_lds16(A  + (size_t)(m0 + r0 + srow)      * Kd + kk + schunk, &As[(r0)      * BK]);
    gl_lds16(A  + (size_t)(m0 + r0 + 16 + srow) * Kd + kk + schunk, &As[(r0 + 16) * BK]);
    gl_lds16(Bt + (size_t)(n0 + r0 + srow)      * Kd + kk + schunk, &Bs[(r0)      * BK]);
    gl_lds16(Bt + (size_t)(n0 + r0 + 16 + srow) * Kd + kk + schunk, &Bs[(r0 + 16) * BK]);
    __syncthreads();                         // waits vmcnt(0): staging complete

    h8v af[4], bfr[4];
#pragma unroll
    for (int i = 0; i < 4; ++i)
      af[i] = *(const h8v*)&As[(wm + i * 16 + fm) * BK + fk];
#pragma unroll
    for (int j = 0; j < 4; ++j)
      bfr[j] = *(const h8v*)&Bs[(wn + j * 16 + fm) * BK + fk];
#pragma unroll
    for (int i = 0; i < 4; ++i)
#pragma unroll
      for (int j = 0; j < 4; ++j)
        acc[i][j] = __builtin_amdgcn_mfma_f32_16x16x32_f16(af[i], bfr[j], acc[i][j], 0, 0, 0);
  }

  // C/D layout (m89-verified, dtype-independent): col = lane&15, row = (lane>>4)*4 + reg
  int rr = (lane >> 4) * 4, cc = lane & 15;
#pragma unroll
  for (int i = 0; i < 4; ++i)
#pragma unroll
    for (int j = 0; j < 4; ++j) {
      size_t base = (size_t)(m0 + wm + i * 16 + rr) * Nd + (n0 + wn + j * 16 + cc);
#pragma unroll
      for (int r = 0; r < 4; ++r) {
        float v = acc[i][j][r];
        if constexpr (OUTF16) ((_Float16*)Cv)[base + (size_t)r * Nd] = (_Float16)v;
        else                  ((float*)Cv)[base + (size_t)r * Nd] = v;
      }
    }
}

// ---------------- MFMA windowed attention ----------------
// Grid (S/64, B*H). Block = 256 = 4 waves; wave w owns q-rows [16w,16w+16).
// Scores: Q(64x64) @ K^T -> 64x80 (banded; full tile computed, band used).
// Softmax: 64 threads, one q-row each, 9-wide band, NO shuffles.
// PV: W(64x96, zero-padded band) @ V(96x64) via MFMA; V read as B[k][n] with
// strided ds_read_u16 (vs row stride 68 breaks the 8-way bank pattern).
__global__ __launch_bounds__(256) void sda_attn_kernel(
    const _Float16* __restrict__ Q, const _Float16* __restrict__ K,
    const _Float16* __restrict__ V, _Float16* __restrict__ O) {
  constexpr int VS  = 68;  // vs row stride (f16): 34 dw, 34%4!=0 -> 4-way max
  constexpr int SCS = 81;  // sc row stride (f32): breaks 4-row group collisions
  __shared__ __align__(16) _Float16 qs[64 * 64];    //  8 KB
  __shared__ __align__(16) _Float16 ks[80 * 64];    // 10 KB (rows 72..79 zero)
  __shared__ __align__(16) _Float16 vs[96 * VS];    // 12.75 KB (rows 72..95 zero)
  __shared__ __align__(16) float    sc[64 * SCS];   // 20.25 KB raw scores
  __shared__ __align__(16) _Float16 wts[64 * 96];   // 12 KB softmax weights (banded)

  int bh = blockIdx.y, b = bh >> 4, h = bh & 15;
  int s0 = blockIdx.x * 64;
  int tid = threadIdx.x;
  size_t headoff = (size_t)b * S_LEN * DM + h * 64;

  // ---- stage ----
  for (int idx = tid; idx < 64 * 8; idx += 256) {       // Q: 64 rows x 8 chunks
    int row = idx >> 3, ch = (idx & 7) * 8;
    *(uint4*)&qs[row * 64 + ch] =
        *(const uint4*)(Q + headoff + (size_t)(s0 + row) * DM + ch);
  }
  for (int idx = tid; idx < 72 * 8; idx += 256) {       // K,V: 72 rows x 8 chunks
    int row = idx >> 3, ch = (idx & 7) * 8;
    int pos = s0 - RAD + row;
    uint4 kv = make_uint4(0, 0, 0, 0), vv = make_uint4(0, 0, 0, 0);
    if (pos >= 0) {
      size_t off = headoff + (size_t)pos * DM + ch;
      kv = *(const uint4*)(K + off);
      vv = *(const uint4*)(V + off);
    }
    *(uint4*)&ks[row * 64 + ch] = kv;
    *(uint2*)&vs[row * VS + ch]     = make_uint2(vv.x, vv.y);  // 8B-aligned (VS*2=136)
    *(uint2*)&vs[row * VS + ch + 4] = make_uint2(vv.z, vv.w);
  }
  if (tid < 64)                                          // ks rows 72..79 -> 0
    *(uint4*)&ks[(72 + (tid >> 3)) * 64 + (tid & 7) * 8] = make_uint4(0, 0, 0, 0);
  for (int idx = tid; idx < 24 * 17; idx += 256) {       // vs rows 72..95 -> 0
    int row = 72 + idx / 17, c = (idx % 17) * 4;
    *(uint2*)&vs[row * VS + c] = make_uint2(0, 0);
  }
  for (int idx = tid; idx < 768; idx += 256)             // wts -> 0 (12 KB)
    ((uint4*)wts)[idx] = make_uint4(0, 0, 0, 0);
  __syncthreads();

  int wid = tid >> 6, lane = tid & 63;
  int fm = lane & 15, fkg = (lane >> 4) * 8;
  int rr = (lane >> 4) * 4, cc = lane & 15;

  // ---- QK^T: wave w -> m-tile w (16 rows) x 5 n-tiles x K=64 (2 steps) ----
  {
    f32x4 accs[5] = {};
    h8v aq0 = *(const h8v*)&qs[(wid * 16 + fm) * 64 + fkg];
    h8v aq1 = *(const h8v*)&qs[(wid * 16 + fm) * 64 + 32 + fkg];
#pragma unroll
    for (int t = 0; t < 5; ++t) {
      h8v bk0 = *(const h8v*)&ks[(t * 16 + fm) * 64 + fkg];
      h8v bk1 = *(const h8v*)&ks[(t * 16 + fm) * 64 + 32 + fkg];
      accs[t] = __builtin_amdgcn_mfma_f32_16x16x32_f16(aq0, bk0, accs[t], 0, 0, 0);
      accs[t] = __builtin_amdgcn_mfma_f32_16x16x32_f16(aq1, bk1, accs[t], 0, 0, 0);
    }
#pragma unroll
    for (int t = 0; t < 5; ++t)
#pragma unroll
      for (int r = 0; r < 4; ++r)
        sc[(wid * 16 + rr + r) * SCS + t * 16 + cc] = accs[t][r];
  }
  __syncthreads();

  // ---- softmax on the 9-wide band: thread r owns q-row r ----
  if (tid < 64) {
    int r = tid, s = s0 + r;
    float e[9], mx = -1e30f;
#pragma unroll
    for (int j = 0; j < 9; ++j) {
      float p = sc[r * SCS + r + j] * INV2T;
      e[j] = (s - RAD + j >= 0) ? p : -1e30f;
      mx = fmaxf(mx, e[j]);
    }
    float se = 0.f;
#pragma unroll
    for (int j = 0; j < 9; ++j) { e[j] = __expf(e[j] - mx); se += e[j]; }
    float inv = 1.f / se;
#pragma unroll
    for (int j = 0; j < 9; ++j)
      wts[r * 96 + r + j] = (_Float16)(e[j] * inv);
  }
  __syncthreads();

  // ---- PV: O(64x64) = W(64x96) @ V(96x64); 3 k-steps ----
  f32x4 acco[4] = {};
#pragma unroll
  for (int step = 0; step < 3; ++step) {
    h8v aw = *(const h8v*)&wts[(wid * 16 + fm) * 96 + step * 32 + fkg];
    int kb = step * 32 + fkg;
#pragma unroll
    for (int t = 0; t < 4; ++t) {
      h8v bv;
#pragma unroll
      for (int j = 0; j < 8; ++j)
        bv[j] = vs[(kb + j) * VS + t * 16 + fm];   // B[k][n], strided u16 reads
      acco[t] = __builtin_amdgcn_mfma_f32_16x16x32_f16(aw, bv, acco[t], 0, 0, 0);
    }
  }
#pragma unroll
  for (int t = 0; t < 4; ++t)
#pragma unroll
    for (int r = 0; r < 4; ++r)
      O[headoff + (size_t)(s0 + wid * 16 + rr + r) * DM + t * 16 + cc] =
          (_Float16)acco[t][r];
}

extern "C" void kernel_launch(void* const* d_in, const int* in_sizes, int n_in,
                              void* d_out, int out_size, void* d_ws, size_t ws_size,
                              hipStream_t stream) {
  (void)in_sizes; (void)n_in; (void)out_size; (void)ws_size;
  const float* x  = (const float*)d_in[0];
  const float* Wq = (const float*)d_in[1];
  const float* Wk = (const float*)d_in[2];
  const float* Wv = (const float*)d_in[3];
  const float* Wo = (const float*)d_in[4];

  char* ws = (char*)d_ws;
  const size_t MB = 1ull << 20;
  _Float16* xh  = (_Float16*)(ws + 0);        // 16 MB
  _Float16* WqT = (_Float16*)(ws + 16 * MB);  // 2 MB each
  _Float16* WkT = (_Float16*)(ws + 18 * MB);
  _Float16* WvT = (_Float16*)(ws + 20 * MB);
  _Float16* WoT = (_Float16*)(ws + 22 * MB);
  _Float16* Qh  = (_Float16*)(ws + 24 * MB);  // 16 MB each
  _Float16* Kh  = (_Float16*)(ws + 40 * MB);
  _Float16* Vh  = (_Float16*)(ws + 56 * MB);
  _Float16* Ah  = (_Float16*)(ws + 72 * MB);  // total 88 MB

  sda_cast_kernel<<<4096, 256, 0, stream>>>(x, xh);
  sda_transcast_kernel<<<dim3(32, 32, 4), dim3(32, 8), 0, stream>>>(
      Wq, Wk, Wv, Wo, WqT, WkT, WvT, WoT);

  // QKV: one launch, z selects weight/output (M=8192, N=1024 -> 8x64 tiles)
  sda_gemm_bt_kernel<true><<<dim3(8, 64, 3), 256, 0, stream>>>(
      xh, WqT, WkT, WvT, Qh, Kh, Vh);
  sda_attn_kernel<<<dim3(64, 32), 256, 0, stream>>>(Qh, Kh, Vh, Ah);
  sda_gemm_bt_kernel<false><<<dim3(8, 64, 1), 256, 0, stream>>>(
      Ah, WoT, WoT, WoT, d_out, d_out, d_out);
}

// Round 5
// 206.189 us; speedup vs baseline: 1.7848x; 1.0407x over previous
//
#include <hip/hip_runtime.h>
#include <stdint.h>

// Problem constants (from reference): B=2, S=4096, D_MODEL=1024, H=16, d_k=64
// RADIUS = ceil(sqrt(4*0.28*ln(1e6))*2) = 8, window = 9 (positions s-8..s)
constexpr int S_LEN = 4096;
constexpr int DM    = 1024;
constexpr int RAD   = 8;
constexpr float INV2T = 1.7857142857142858f; // 1/(2*0.28)

constexpr int BM = 128, BN = 128, BK = 32;

// fp16 path: 11 mantissa bits (8x less rounding than bf16) at the SAME MFMA rate.
typedef _Float16 h8v __attribute__((ext_vector_type(8)));  // 8 f16 (4 VGPRs) MFMA frag
typedef float f32x4  __attribute__((ext_vector_type(4)));  // MFMA accumulator

// async global->LDS, 16B/lane. LDS dst is wave-uniform base + lane*16 (HW rule).
static __device__ __forceinline__ void gl_lds16(const void* gp, void* lp) {
  auto g = (const __attribute__((address_space(1))) void*)(uintptr_t)gp;
  auto l = (__attribute__((address_space(3))) void*)(uint32_t)(uintptr_t)lp;
  __builtin_amdgcn_global_load_lds(g, l, 16, 0, 0);
}

// ---------------- cast x (fp32) -> fp16, 8 elems/thread ----------------
__global__ __launch_bounds__(256) void sda_cast_kernel(const float* __restrict__ X,
                                                       _Float16* __restrict__ Y) {
  int i = blockIdx.x * 256 + threadIdx.x;
  const float4* x4 = (const float4*)X;
  float4 a = x4[2 * i], b = x4[2 * i + 1];
  float f[8] = {a.x, a.y, a.z, a.w, b.x, b.y, b.z, b.w};
  union { _Float16 h[8]; uint4 v; } o;
#pragma unroll
  for (int j = 0; j < 8; ++j) o.h[j] = (_Float16)f[j];   // v_cvt_f16_f32, RNE
  ((uint4*)Y)[i] = o.v;
}

// ---------------- W (K x N fp32) -> W^T (N x K fp16), all 4 weights ----------
__global__ __launch_bounds__(256) void sda_transcast_kernel(
    const float* __restrict__ W0, const float* __restrict__ W1,
    const float* __restrict__ W2, const float* __restrict__ W3,
    _Float16* __restrict__ T0, _Float16* __restrict__ T1,
    _Float16* __restrict__ T2, _Float16* __restrict__ T3) {
  __shared__ float t[32][33];
  const float* W = blockIdx.z == 0 ? W0 : (blockIdx.z == 1 ? W1 : (blockIdx.z == 2 ? W2 : W3));
  _Float16*    T = blockIdx.z == 0 ? T0 : (blockIdx.z == 1 ? T1 : (blockIdx.z == 2 ? T2 : T3));
  int tx = threadIdx.x, ty = threadIdx.y;     // block (32,8)
  int n0 = blockIdx.x * 32, k0 = blockIdx.y * 32;
#pragma unroll
  for (int i = 0; i < 4; ++i)
    t[ty + 8 * i][tx] = W[(size_t)(k0 + ty + 8 * i) * DM + n0 + tx];
  __syncthreads();
#pragma unroll
  for (int i = 0; i < 4; ++i)
    T[(size_t)(n0 + ty + 8 * i) * DM + k0 + tx] = (_Float16)t[tx][ty + 8 * i];
}

// ------- fp16 GEMM, XCD-swizzled: C[M,N] = A * B, B given as B^T[N,K] -------
// m97 recipe (128x128 tile, BK=32, 4 waves 2x2, 16x16x32 f16 MFMA,
// global_load_lds width=16) + XCD-aware block swizzle:
//   1D grid, xcd = blk&7 gets y-stripe [xcd*8, xcd*8+8) -> per-XCD A working
//   set 2 MB (L2-resident); x-tiles swept x-major so one 256 KB B-tile is
//   live at a time. Cuts A re-fetch from ~8x to ~1x per XCD.
// N may span multiple 1024-wide outputs (QKV fused: N=3072); output pointer
// selected by n0>>10, column = n0&1023.
template <bool OUTF16>
__global__ __launch_bounds__(256) void sda_gemm_swz_kernel(
    const _Float16* __restrict__ A, const _Float16* __restrict__ Bt,
    void* __restrict__ C0, void* __restrict__ C1, void* __restrict__ C2) {
  constexpr int Kd = DM;
  __shared__ __align__(16) _Float16 As[BM * BK];  // [m][k], 64B rows
  __shared__ __align__(16) _Float16 Bs[BN * BK];  // [n][k]

  int blk = blockIdx.x;
  int xcd = blk & 7, slot = blk >> 3;   // slots per XCD = NT*8
  int xt = slot >> 3, ys = slot & 7;    // x-major within XCD
  int yt = (xcd << 3) | ys;             // y-stripe per XCD
  int m0 = yt * BM, n0 = xt * BN;

  int tid = threadIdx.x, wid = tid >> 6, lane = tid & 63;
  int srow = lane >> 2;          // staging row within 16 (lane/4)
  int schunk = (lane & 3) * 8;   // staging k-chunk (8 f16 = 16B)
  int wm = (wid >> 1) * 64, wn = (wid & 1) * 64;
  int fm = lane & 15, fk = (lane >> 4) * 8;  // MFMA frag: m/n = lane&15, k = quad*8

  f32x4 acc[4][4] = {};

  for (int kt = 0; kt < Kd / BK; ++kt) {
    if (kt) __syncthreads();                 // protect LDS before overwrite
    int kk = kt * BK;
    int r0 = wid * 32;                       // each wave stages 32 rows of A and of B
    gl_lds16(A  + (size_t)(m0 + r0 + srow)      * Kd + kk + schunk, &As[(r0)      * BK]);
    gl_lds16(A  + (size_t)(m0 + r0 + 16 + srow) * Kd + kk + schunk, &As[(r0 + 16) * BK]);
    gl_lds16(Bt + (size_t)(n0 + r0 + srow)      * Kd + kk + schunk, &Bs[(r0)      * BK]);
    gl_lds16(Bt + (size_t)(n0 + r0 + 16 + srow) * Kd + kk + schunk, &Bs[(r0 + 16) * BK]);
    __syncthreads();                         // waits vmcnt(0): staging complete

    h8v af[4], bfr[4];
#pragma unroll
    for (int i = 0; i < 4; ++i)
      af[i] = *(const h8v*)&As[(wm + i * 16 + fm) * BK + fk];
#pragma unroll
    for (int j = 0; j < 4; ++j)
      bfr[j] = *(const h8v*)&Bs[(wn + j * 16 + fm) * BK + fk];
#pragma unroll
    for (int i = 0; i < 4; ++i)
#pragma unroll
      for (int j = 0; j < 4; ++j)
        acc[i][j] = __builtin_amdgcn_mfma_f32_16x16x32_f16(af[i], bfr[j], acc[i][j], 0, 0, 0);
  }

  // Output select: which 1024-wide matrix this n-tile belongs to (QKV fusion).
  int which = n0 >> 10, nc = n0 & 1023;
  void* Cv = which == 0 ? C0 : (which == 1 ? C1 : C2);

  // C/D layout (m89-verified, dtype-independent): col = lane&15, row = (lane>>4)*4 + reg
  int rr = (lane >> 4) * 4, cc = lane & 15;
#pragma unroll
  for (int i = 0; i < 4; ++i)
#pragma unroll
    for (int j = 0; j < 4; ++j) {
      size_t base = (size_t)(m0 + wm + i * 16 + rr) * DM + (nc + wn + j * 16 + cc);
#pragma unroll
      for (int r = 0; r < 4; ++r) {
        float v = acc[i][j][r];
        if constexpr (OUTF16) ((_Float16*)Cv)[base + (size_t)r * DM] = (_Float16)v;
        else                  ((float*)Cv)[base + (size_t)r * DM] = v;
      }
    }
}

// ---------------- MFMA windowed attention ----------------
// Grid (S/64, B*H). Block = 256 = 4 waves; wave w owns q-rows [16w,16w+16).
// Scores: Q(64x64) @ K^T -> 64x80 (banded; full tile computed, band used).
// Softmax: 64 threads, one q-row each, 9-wide band, NO shuffles.
// PV: W(64x96, zero-padded band) @ V(96x64) via MFMA; V read as B[k][n] with
// strided ds_read_u16 (vs row stride 68 breaks the 8-way bank pattern).
__global__ __launch_bounds__(256) void sda_attn_kernel(
    const _Float16* __restrict__ Q, const _Float16* __restrict__ K,
    const _Float16* __restrict__ V, _Float16* __restrict__ O) {
  constexpr int VS  = 68;  // vs row stride (f16): 34 dw, 34%4!=0 -> 4-way max
  constexpr int SCS = 81;  // sc row stride (f32): breaks 4-row group collisions
  __shared__ __align__(16) _Float16 qs[64 * 64];    //  8 KB
  __shared__ __align__(16) _Float16 ks[80 * 64];    // 10 KB (rows 72..79 zero)
  __shared__ __align__(16) _Float16 vs[96 * VS];    // 12.75 KB (rows 72..95 zero)
  __shared__ __align__(16) float    sc[64 * SCS];   // 20.25 KB raw scores
  __shared__ __align__(16) _Float16 wts[64 * 96];   // 12 KB softmax weights (banded)

  int bh = blockIdx.y, b = bh >> 4, h = bh & 15;
  int s0 = blockIdx.x * 64;
  int tid = threadIdx.x;
  size_t headoff = (size_t)b * S_LEN * DM + h * 64;

  // ---- stage ----
  for (int idx = tid; idx < 64 * 8; idx += 256) {       // Q: 64 rows x 8 chunks
    int row = idx >> 3, ch = (idx & 7) * 8;
    *(uint4*)&qs[row * 64 + ch] =
        *(const uint4*)(Q + headoff + (size_t)(s0 + row) * DM + ch);
  }
  for (int idx = tid; idx < 72 * 8; idx += 256) {       // K,V: 72 rows x 8 chunks
    int row = idx >> 3, ch = (idx & 7) * 8;
    int pos = s0 - RAD + row;
    uint4 kv = make_uint4(0, 0, 0, 0), vv = make_uint4(0, 0, 0, 0);
    if (pos >= 0) {
      size_t off = headoff + (size_t)pos * DM + ch;
      kv = *(const uint4*)(K + off);
      vv = *(const uint4*)(V + off);
    }
    *(uint4*)&ks[row * 64 + ch] = kv;
    *(uint2*)&vs[row * VS + ch]     = make_uint2(vv.x, vv.y);  // 8B-aligned (VS*2=136)
    *(uint2*)&vs[row * VS + ch + 4] = make_uint2(vv.z, vv.w);
  }
  if (tid < 64)                                          // ks rows 72..79 -> 0
    *(uint4*)&ks[(72 + (tid >> 3)) * 64 + (tid & 7) * 8] = make_uint4(0, 0, 0, 0);
  for (int idx = tid; idx < 24 * 17; idx += 256) {       // vs rows 72..95 -> 0
    int row = 72 + idx / 17, c = (idx % 17) * 4;
    *(uint2*)&vs[row * VS + c] = make_uint2(0, 0);
  }
  for (int idx = tid; idx < 768; idx += 256)             // wts -> 0 (12 KB)
    ((uint4*)wts)[idx] = make_uint4(0, 0, 0, 0);
  __syncthreads();

  int wid = tid >> 6, lane = tid & 63;
  int fm = lane & 15, fkg = (lane >> 4) * 8;
  int rr = (lane >> 4) * 4, cc = lane & 15;

  // ---- QK^T: wave w -> m-tile w (16 rows) x 5 n-tiles x K=64 (2 steps) ----
  {
    f32x4 accs[5] = {};
    h8v aq0 = *(const h8v*)&qs[(wid * 16 + fm) * 64 + fkg];
    h8v aq1 = *(const h8v*)&qs[(wid * 16 + fm) * 64 + 32 + fkg];
#pragma unroll
    for (int t = 0; t < 5; ++t) {
      h8v bk0 = *(const h8v*)&ks[(t * 16 + fm) * 64 + fkg];
      h8v bk1 = *(const h8v*)&ks[(t * 16 + fm) * 64 + 32 + fkg];
      accs[t] = __builtin_amdgcn_mfma_f32_16x16x32_f16(aq0, bk0, accs[t], 0, 0, 0);
      accs[t] = __builtin_amdgcn_mfma_f32_16x16x32_f16(aq1, bk1, accs[t], 0, 0, 0);
    }
#pragma unroll
    for (int t = 0; t < 5; ++t)
#pragma unroll
      for (int r = 0; r < 4; ++r)
        sc[(wid * 16 + rr + r) * SCS + t * 16 + cc] = accs[t][r];
  }
  __syncthreads();

  // ---- softmax on the 9-wide band: thread r owns q-row r ----
  if (tid < 64) {
    int r = tid, s = s0 + r;
    float e[9], mx = -1e30f;
#pragma unroll
    for (int j = 0; j < 9; ++j) {
      float p = sc[r * SCS + r + j] * INV2T;
      e[j] = (s - RAD + j >= 0) ? p : -1e30f;
      mx = fmaxf(mx, e[j]);
    }
    float se = 0.f;
#pragma unroll
    for (int j = 0; j < 9; ++j) { e[j] = __expf(e[j] - mx); se += e[j]; }
    float inv = 1.f / se;
#pragma unroll
    for (int j = 0; j < 9; ++j)
      wts[r * 96 + r + j] = (_Float16)(e[j] * inv);
  }
  __syncthreads();

  // ---- PV: O(64x64) = W(64x96) @ V(96x64); 3 k-steps ----
  f32x4 acco[4] = {};
#pragma unroll
  for (int step = 0; step < 3; ++step) {
    h8v aw = *(const h8v*)&wts[(wid * 16 + fm) * 96 + step * 32 + fkg];
    int kb = step * 32 + fkg;
#pragma unroll
    for (int t = 0; t < 4; ++t) {
      h8v bv;
#pragma unroll
      for (int j = 0; j < 8; ++j)
        bv[j] = vs[(kb + j) * VS + t * 16 + fm];   // B[k][n], strided u16 reads
      acco[t] = __builtin_amdgcn_mfma_f32_16x16x32_f16(aw, bv, acco[t], 0, 0, 0);
    }
  }
#pragma unroll
  for (int t = 0; t < 4; ++t)
#pragma unroll
    for (int r = 0; r < 4; ++r)
      O[headoff + (size_t)(s0 + wid * 16 + rr + r) * DM + t * 16 + cc] =
          (_Float16)acco[t][r];
}

extern "C" void kernel_launch(void* const* d_in, const int* in_sizes, int n_in,
                              void* d_out, int out_size, void* d_ws, size_t ws_size,
                              hipStream_t stream) {
  (void)in_sizes; (void)n_in; (void)out_size; (void)ws_size;
  const float* x  = (const float*)d_in[0];
  const float* Wq = (const float*)d_in[1];
  const float* Wk = (const float*)d_in[2];
  const float* Wv = (const float*)d_in[3];
  const float* Wo = (const float*)d_in[4];

  char* ws = (char*)d_ws;
  const size_t MB = 1ull << 20;
  _Float16* xh    = (_Float16*)(ws + 0);        // 16 MB
  _Float16* WqkvT = (_Float16*)(ws + 16 * MB);  // 6 MB: Wq^T|Wk^T|Wv^T rows 0..3071
  _Float16* WoT   = (_Float16*)(ws + 22 * MB);  // 2 MB
  _Float16* Qh    = (_Float16*)(ws + 24 * MB);  // 16 MB each
  _Float16* Kh    = (_Float16*)(ws + 40 * MB);
  _Float16* Vh    = (_Float16*)(ws + 56 * MB);
  _Float16* Ah    = (_Float16*)(ws + 72 * MB);  // total 88 MB

  sda_cast_kernel<<<4096, 256, 0, stream>>>(x, xh);
  sda_transcast_kernel<<<dim3(32, 32, 4), dim3(32, 8), 0, stream>>>(
      Wq, Wk, Wv, Wo,
      WqkvT, WqkvT + (size_t)DM * DM, WqkvT + 2ull * DM * DM, WoT);

  // QKV fused: M=8192, N=3072 -> 24 x-tiles * 64 y-tiles = 1536 blocks (1D, swizzled)
  sda_gemm_swz_kernel<true><<<1536, 256, 0, stream>>>(xh, WqkvT, Qh, Kh, Vh);
  sda_attn_kernel<<<dim3(64, 32), 256, 0, stream>>>(Qh, Kh, Vh, Ah);
  // Wo: N=1024 -> 8 x-tiles * 64 y-tiles = 512 blocks
  sda_gemm_swz_kernel<false><<<512, 256, 0, stream>>>(Ah, WoT, d_out, d_out, d_out);
}

// Round 6
// 190.210 us; speedup vs baseline: 1.9347x; 1.0840x over previous
//
#include <hip/hip_runtime.h>
#include <stdint.h>

// Problem constants (from reference): B=2, S=4096, D_MODEL=1024, H=16, d_k=64
// RADIUS = ceil(sqrt(4*0.28*ln(1e6))*2) = 8, window = 9 (positions s-8..s)
constexpr int S_LEN = 4096;
constexpr int DM    = 1024;
constexpr int RAD   = 8;
constexpr float INV2T = 1.7857142857142858f; // 1/(2*0.28)

constexpr int BM = 128, BN = 128, BK = 64;   // BK=64: 32 MFMA/barrier (AITER density)

// fp16 path: 11 mantissa bits (8x less rounding than bf16) at the SAME MFMA rate.
typedef _Float16 h8v __attribute__((ext_vector_type(8)));  // 8 f16 (4 VGPRs) MFMA frag
typedef float f32x4  __attribute__((ext_vector_type(4)));  // MFMA accumulator

// async global->LDS, 16B/lane. LDS dst is wave-uniform base + lane*16 (HW rule).
static __device__ __forceinline__ void gl_lds16(const void* gp, void* lp) {
  auto g = (const __attribute__((address_space(1))) void*)(uintptr_t)gp;
  auto l = (__attribute__((address_space(3))) void*)(uint32_t)(uintptr_t)lp;
  __builtin_amdgcn_global_load_lds(g, l, 16, 0, 0);
}

// ---------------- cast x (fp32) -> fp16, 8 elems/thread ----------------
__global__ __launch_bounds__(256) void sda_cast_kernel(const float* __restrict__ X,
                                                       _Float16* __restrict__ Y) {
  int i = blockIdx.x * 256 + threadIdx.x;
  const float4* x4 = (const float4*)X;
  float4 a = x4[2 * i], b = x4[2 * i + 1];
  float f[8] = {a.x, a.y, a.z, a.w, b.x, b.y, b.z, b.w};
  union { _Float16 h[8]; uint4 v; } o;
#pragma unroll
  for (int j = 0; j < 8; ++j) o.h[j] = (_Float16)f[j];   // v_cvt_f16_f32, RNE
  ((uint4*)Y)[i] = o.v;
}

// ---------------- W (K x N fp32) -> W^T (N x K fp16), all 4 weights ----------
__global__ __launch_bounds__(256) void sda_transcast_kernel(
    const float* __restrict__ W0, const float* __restrict__ W1,
    const float* __restrict__ W2, const float* __restrict__ W3,
    _Float16* __restrict__ T0, _Float16* __restrict__ T1,
    _Float16* __restrict__ T2, _Float16* __restrict__ T3) {
  __shared__ float t[32][33];
  const float* W = blockIdx.z == 0 ? W0 : (blockIdx.z == 1 ? W1 : (blockIdx.z == 2 ? W2 : W3));
  _Float16*    T = blockIdx.z == 0 ? T0 : (blockIdx.z == 1 ? T1 : (blockIdx.z == 2 ? T2 : T3));
  int tx = threadIdx.x, ty = threadIdx.y;     // block (32,8)
  int n0 = blockIdx.x * 32, k0 = blockIdx.y * 32;
#pragma unroll
  for (int i = 0; i < 4; ++i)
    t[ty + 8 * i][tx] = W[(size_t)(k0 + ty + 8 * i) * DM + n0 + tx];
  __syncthreads();
#pragma unroll
  for (int i = 0; i < 4; ++i)
    T[(size_t)(n0 + ty + 8 * i) * DM + k0 + tx] = (_Float16)t[tx][ty + 8 * i];
}

// ------- fp16 GEMM, XCD-swizzled, BK=64: C[M,N] = A * B^T[N,K] -------
// 128x128 tile, BK=64 (16 K-iters, 32 MFMA/barrier), 4 waves 2x2,
// global_load_lds width=16. LDS rows are 128 B; to kill the resulting
// ds_read_b128 bank aliasing, chunk c of row r holds logical chunk c^(r&7)
// (we permute the GLOBAL source per lane — the LDS dst of global_load_lds
// is fixed at base+lane*16). XCD swizzle: xcd = blk&7 owns an 8-row A-stripe,
// x-major B sweep. QKV fused via n0>>10 output select.
template <bool OUTF16>
__global__ __launch_bounds__(256) void sda_gemm_swz_kernel(
    const _Float16* __restrict__ A, const _Float16* __restrict__ Bt,
    void* __restrict__ C0, void* __restrict__ C1, void* __restrict__ C2) {
  constexpr int Kd = DM;
  __shared__ __align__(16) _Float16 As[BM * BK];  // 16 KB, [m][k] 128B rows, chunk-XORed
  __shared__ __align__(16) _Float16 Bs[BN * BK];  // 16 KB

  int blk = blockIdx.x;
  int xcd = blk & 7, slot = blk >> 3;
  int xt = slot >> 3, ys = slot & 7;    // x-major within XCD
  int yt = (xcd << 3) | ys;             // y-stripe per XCD
  int m0 = yt * BM, n0 = xt * BN;

  int tid = threadIdx.x, wid = tid >> 6, lane = tid & 63;
  int srow = lane >> 3;                       // staging row within 8
  int sgk = ((lane & 7) ^ (srow & 7)) * 8;    // XOR-permuted global k-chunk
  int wm = (wid >> 1) * 64, wn = (wid & 1) * 64;
  int fm = lane & 15, fc = lane >> 4;         // frag: m/n = lane&15, k-chunk = lane>>4

  f32x4 acc[4][4] = {};

  for (int kt = 0; kt < Kd / BK; ++kt) {
    if (kt) __syncthreads();                 // protect LDS before overwrite
    int kk = kt * BK;
    int r0 = wid * 32;                       // each wave stages 32 rows of A and of B
#pragma unroll
    for (int i = 0; i < 4; ++i) {
      gl_lds16(A  + (size_t)(m0 + r0 + i * 8 + srow) * Kd + kk + sgk, &As[(r0 + i * 8) * BK]);
      gl_lds16(Bt + (size_t)(n0 + r0 + i * 8 + srow) * Kd + kk + sgk, &Bs[(r0 + i * 8) * BK]);
    }
    __syncthreads();                         // waits vmcnt(0): staging complete

#pragma unroll
    for (int ks = 0; ks < 2; ++ks) {         // two k=32 halves per tile
      h8v af[4], bfr[4];
#pragma unroll
      for (int i = 0; i < 4; ++i) {
        int row = wm + i * 16 + fm;
        af[i] = *(const h8v*)&As[row * BK + (((ks * 4 + fc) ^ (row & 7)) * 8)];
      }
#pragma unroll
      for (int j = 0; j < 4; ++j) {
        int row = wn + j * 16 + fm;
        bfr[j] = *(const h8v*)&Bs[row * BK + (((ks * 4 + fc) ^ (row & 7)) * 8)];
      }
#pragma unroll
      for (int i = 0; i < 4; ++i)
#pragma unroll
        for (int j = 0; j < 4; ++j)
          acc[i][j] = __builtin_amdgcn_mfma_f32_16x16x32_f16(af[i], bfr[j], acc[i][j], 0, 0, 0);
    }
  }

  // Output select: which 1024-wide matrix this n-tile belongs to (QKV fusion).
  int which = n0 >> 10, nc = n0 & 1023;
  void* Cv = which == 0 ? C0 : (which == 1 ? C1 : C2);

  // C/D layout (m89-verified, dtype-independent): col = lane&15, row = (lane>>4)*4 + reg
  int rr = (lane >> 4) * 4, cc = lane & 15;
#pragma unroll
  for (int i = 0; i < 4; ++i)
#pragma unroll
    for (int j = 0; j < 4; ++j) {
      size_t base = (size_t)(m0 + wm + i * 16 + rr) * DM + (nc + wn + j * 16 + cc);
#pragma unroll
      for (int r = 0; r < 4; ++r) {
        float v = acc[i][j][r];
        if constexpr (OUTF16) ((_Float16*)Cv)[base + (size_t)r * DM] = (_Float16)v;
        else                  ((float*)Cv)[base + (size_t)r * DM] = v;
      }
    }
}

// ---------------- MFMA windowed attention ----------------
// Grid (S/64, B*H). Block = 256 = 4 waves; wave w owns q-rows [16w,16w+16).
// Band structure: q-row r attends score-cols [r, r+8] -> wave w only needs
// score n-tiles w and w+1 (2 MFMA pairs, not 5) and a 16x33 per-wave score
// buffer (8.4 KB total vs 20.7 KB full). LDS ~50 KB -> 3 blocks/CU.
__global__ __launch_bounds__(256) void sda_attn_kernel(
    const _Float16* __restrict__ Q, const _Float16* __restrict__ K,
    const _Float16* __restrict__ V, _Float16* __restrict__ O) {
  constexpr int VS  = 68;  // vs row stride (f16): 34 dw, 34%4!=0 -> 4-way max
  __shared__ __align__(16) _Float16 qs[64 * 64];      //  8 KB
  __shared__ __align__(16) _Float16 ks[80 * 64];      // 10 KB (rows 72..79 zero)
  __shared__ __align__(16) _Float16 vs[96 * VS];      // 12.75 KB (rows 72..95 zero)
  __shared__ __align__(16) float    scb[4 * 16 * 33]; //  8.25 KB per-wave scores
  __shared__ __align__(16) _Float16 wts[64 * 96];     // 12 KB softmax weights (banded)

  int bh = blockIdx.y, b = bh >> 4, h = bh & 15;
  int s0 = blockIdx.x * 64;
  int tid = threadIdx.x;
  size_t headoff = (size_t)b * S_LEN * DM + h * 64;

  // ---- stage ----
  for (int idx = tid; idx < 64 * 8; idx += 256) {       // Q: 64 rows x 8 chunks
    int row = idx >> 3, ch = (idx & 7) * 8;
    *(uint4*)&qs[row * 64 + ch] =
        *(const uint4*)(Q + headoff + (size_t)(s0 + row) * DM + ch);
  }
  for (int idx = tid; idx < 72 * 8; idx += 256) {       // K,V: 72 rows x 8 chunks
    int row = idx >> 3, ch = (idx & 7) * 8;
    int pos = s0 - RAD + row;
    uint4 kv = make_uint4(0, 0, 0, 0), vv = make_uint4(0, 0, 0, 0);
    if (pos >= 0) {
      size_t off = headoff + (size_t)pos * DM + ch;
      kv = *(const uint4*)(K + off);
      vv = *(const uint4*)(V + off);
    }
    *(uint4*)&ks[row * 64 + ch] = kv;
    *(uint2*)&vs[row * VS + ch]     = make_uint2(vv.x, vv.y);  // 8B-aligned (VS*2=136)
    *(uint2*)&vs[row * VS + ch + 4] = make_uint2(vv.z, vv.w);
  }
  if (tid < 64)                                          // ks rows 72..79 -> 0
    *(uint4*)&ks[(72 + (tid >> 3)) * 64 + (tid & 7) * 8] = make_uint4(0, 0, 0, 0);
  for (int idx = tid; idx < 24 * 17; idx += 256) {       // vs rows 72..95 -> 0
    int row = 72 + idx / 17, c = (idx % 17) * 4;
    *(uint2*)&vs[row * VS + c] = make_uint2(0, 0);
  }
  for (int idx = tid; idx < 768; idx += 256)             // wts -> 0 (12 KB)
    ((uint4*)wts)[idx] = make_uint4(0, 0, 0, 0);
  __syncthreads();

  int wid = tid >> 6, lane = tid & 63;
  int fm = lane & 15, fkg = (lane >> 4) * 8;
  int rr = (lane >> 4) * 4, cc = lane & 15;

  // ---- QK^T: wave w -> m-tile w (16 rows) x n-tiles {w, w+1} x K=64 ----
  {
    f32x4 accs[2] = {};
    h8v aq0 = *(const h8v*)&qs[(wid * 16 + fm) * 64 + fkg];
    h8v aq1 = *(const h8v*)&qs[(wid * 16 + fm) * 64 + 32 + fkg];
#pragma unroll
    for (int ti = 0; ti < 2; ++ti) {
      int t = wid + ti;
      h8v bk0 = *(const h8v*)&ks[(t * 16 + fm) * 64 + fkg];
      h8v bk1 = *(const h8v*)&ks[(t * 16 + fm) * 64 + 32 + fkg];
      accs[ti] = __builtin_amdgcn_mfma_f32_16x16x32_f16(aq0, bk0, accs[ti], 0, 0, 0);
      accs[ti] = __builtin_amdgcn_mfma_f32_16x16x32_f16(aq1, bk1, accs[ti], 0, 0, 0);
    }
#pragma unroll
    for (int ti = 0; ti < 2; ++ti)
#pragma unroll
      for (int r = 0; r < 4; ++r)
        scb[wid * 528 + (rr + r) * 33 + ti * 16 + cc] = accs[ti][r];
  }
  __syncthreads();

  // ---- softmax on the 9-wide band: thread r owns q-row r ----
  // global score-col of (q-row r, j) = r + j; local col in wave (r>>4)'s
  // buffer = (r&15) + j  (max 15+8=23 < 32).
  if (tid < 64) {
    int r = tid, s = s0 + r;
    const float* my = &scb[(r >> 4) * 528 + (r & 15) * 33 + (r & 15)];
    float e[9], mx = -1e30f;
#pragma unroll
    for (int j = 0; j < 9; ++j) {
      float p = my[j] * INV2T;
      e[j] = (s - RAD + j >= 0) ? p : -1e30f;
      mx = fmaxf(mx, e[j]);
    }
    float se = 0.f;
#pragma unroll
    for (int j = 0; j < 9; ++j) { e[j] = __expf(e[j] - mx); se += e[j]; }
    float inv = 1.f / se;
#pragma unroll
    for (int j = 0; j < 9; ++j)
      wts[r * 96 + r + j] = (_Float16)(e[j] * inv);
  }
  __syncthreads();

  // ---- PV: O(64x64) = W(64x96) @ V(96x64); 3 k-steps ----
  f32x4 acco[4] = {};
#pragma unroll
  for (int step = 0; step < 3; ++step) {
    h8v aw = *(const h8v*)&wts[(wid * 16 + fm) * 96 + step * 32 + fkg];
    int kb = step * 32 + fkg;
#pragma unroll
    for (int t = 0; t < 4; ++t) {
      h8v bv;
#pragma unroll
      for (int j = 0; j < 8; ++j)
        bv[j] = vs[(kb + j) * VS + t * 16 + fm];   // B[k][n], strided u16 reads
      acco[t] = __builtin_amdgcn_mfma_f32_16x16x32_f16(aw, bv, acco[t], 0, 0, 0);
    }
  }
#pragma unroll
  for (int t = 0; t < 4; ++t)
#pragma unroll
    for (int r = 0; r < 4; ++r)
      O[headoff + (size_t)(s0 + wid * 16 + rr + r) * DM + t * 16 + cc] =
          (_Float16)acco[t][r];
}

extern "C" void kernel_launch(void* const* d_in, const int* in_sizes, int n_in,
                              void* d_out, int out_size, void* d_ws, size_t ws_size,
                              hipStream_t stream) {
  (void)in_sizes; (void)n_in; (void)out_size; (void)ws_size;
  const float* x  = (const float*)d_in[0];
  const float* Wq = (const float*)d_in[1];
  const float* Wk = (const float*)d_in[2];
  const float* Wv = (const float*)d_in[3];
  const float* Wo = (const float*)d_in[4];

  char* ws = (char*)d_ws;
  const size_t MB = 1ull << 20;
  _Float16* xh    = (_Float16*)(ws + 0);        // 16 MB
  _Float16* WqkvT = (_Float16*)(ws + 16 * MB);  // 6 MB: Wq^T|Wk^T|Wv^T rows 0..3071
  _Float16* WoT   = (_Float16*)(ws + 22 * MB);  // 2 MB
  _Float16* Qh    = (_Float16*)(ws + 24 * MB);  // 16 MB each
  _Float16* Kh    = (_Float16*)(ws + 40 * MB);
  _Float16* Vh    = (_Float16*)(ws + 56 * MB);
  _Float16* Ah    = (_Float16*)(ws + 72 * MB);  // total 88 MB

  sda_cast_kernel<<<4096, 256, 0, stream>>>(x, xh);
  sda_transcast_kernel<<<dim3(32, 32, 4), dim3(32, 8), 0, stream>>>(
      Wq, Wk, Wv, Wo,
      WqkvT, WqkvT + (size_t)DM * DM, WqkvT + 2ull * DM * DM, WoT);

  // QKV fused: M=8192, N=3072 -> 24 x-tiles * 64 y-tiles = 1536 blocks (1D, swizzled)
  sda_gemm_swz_kernel<true><<<1536, 256, 0, stream>>>(xh, WqkvT, Qh, Kh, Vh);
  sda_attn_kernel<<<dim3(64, 32), 256, 0, stream>>>(Qh, Kh, Vh, Ah);
  // Wo: N=1024 -> 8 x-tiles * 64 y-tiles = 512 blocks
  sda_gemm_swz_kernel<false><<<512, 256, 0, stream>>>(Ah, WoT, d_out, d_out, d_out);
}

// Round 7
// 189.908 us; speedup vs baseline: 1.9378x; 1.0016x over previous
//
#include <hip/hip_runtime.h>
#include <stdint.h>

// Problem constants (from reference): B=2, S=4096, D_MODEL=1024, H=16, d_k=64
// RADIUS = ceil(sqrt(4*0.28*ln(1e6))*2) = 8, window = 9 (positions s-8..s)
constexpr int S_LEN = 4096;
constexpr int DM    = 1024;
constexpr int RAD   = 8;
constexpr float INV2T = 1.7857142857142858f; // 1/(2*0.28)

constexpr int BM = 128, BN = 128, BK = 64;   // BK=64: 32 MFMA/barrier (AITER density)

// fp16 path: 11 mantissa bits (8x less rounding than bf16) at the SAME MFMA rate.
typedef _Float16 h8v __attribute__((ext_vector_type(8)));  // 8 f16 (4 VGPRs) MFMA frag
typedef float f32x4  __attribute__((ext_vector_type(4)));  // MFMA accumulator

// async global->LDS, 16B/lane. LDS dst is wave-uniform base + lane*16 (HW rule).
static __device__ __forceinline__ void gl_lds16(const void* gp, void* lp) {
  auto g = (const __attribute__((address_space(1))) void*)(uintptr_t)gp;
  auto l = (__attribute__((address_space(3))) void*)(uint32_t)(uintptr_t)lp;
  __builtin_amdgcn_global_load_lds(g, l, 16, 0, 0);
}

// ---------------- prep: x->fp16 cast + 4x W transpose-cast, one launch -------
// grid (32,32,8) block (32,8). z<4: W_z (KxN fp32) -> T_z (NxK fp16).
// z>=4: x cast slice (z-4): 1024 blocks x 2048 elems.
__global__ __launch_bounds__(256) void sda_prep_kernel(
    const float* __restrict__ X, _Float16* __restrict__ XH,
    const float* __restrict__ W0, const float* __restrict__ W1,
    const float* __restrict__ W2, const float* __restrict__ W3,
    _Float16* __restrict__ T0, _Float16* __restrict__ T1,
    _Float16* __restrict__ T2, _Float16* __restrict__ T3) {
  __shared__ float t[32][33];
  int z = blockIdx.z;
  int tx = threadIdx.x, ty = threadIdx.y;
  if (z < 4) {
    const float* W = z == 0 ? W0 : (z == 1 ? W1 : (z == 2 ? W2 : W3));
    _Float16*    T = z == 0 ? T0 : (z == 1 ? T1 : (z == 2 ? T2 : T3));
    int n0 = blockIdx.x * 32, k0 = blockIdx.y * 32;
#pragma unroll
    for (int i = 0; i < 4; ++i)
      t[ty + 8 * i][tx] = W[(size_t)(k0 + ty + 8 * i) * DM + n0 + tx];
    __syncthreads();
#pragma unroll
    for (int i = 0; i < 4; ++i)
      T[(size_t)(n0 + ty + 8 * i) * DM + k0 + tx] = (_Float16)t[tx][ty + 8 * i];
  } else {
    int blk = (z - 4) * 1024 + blockIdx.y * 32 + blockIdx.x;
    int i = blk * 256 + ty * 32 + tx;
    const float4* x4 = (const float4*)X;
    float4 a = x4[2 * i], b = x4[2 * i + 1];
    float f[8] = {a.x, a.y, a.z, a.w, b.x, b.y, b.z, b.w};
    union { _Float16 h[8]; uint4 v; } o;
#pragma unroll
    for (int j = 0; j < 8; ++j) o.h[j] = (_Float16)f[j];
    ((uint4*)XH)[i] = o.v;
  }
}

// ------- fp16 GEMM, XCD-swizzled, BK=64: C[M,N] = A * B^T[N,K] -------
// 128x128 tile, BK=64 (16 K-iters, 32 MFMA/barrier), 4 waves 2x2,
// global_load_lds width=16, XOR chunk swizzle (R6: conflicts -> 0).
// XCD swizzle: xcd = blk&7 owns an 8-row A-stripe, x-major B sweep.
// QKV fused via n0>>10 output select.
__global__ __launch_bounds__(256) void sda_gemm_swz_kernel(
    const _Float16* __restrict__ A, const _Float16* __restrict__ Bt,
    _Float16* __restrict__ C0, _Float16* __restrict__ C1,
    _Float16* __restrict__ C2) {
  constexpr int Kd = DM;
  __shared__ __align__(16) _Float16 As[BM * BK];  // 16 KB, [m][k] 128B rows, chunk-XORed
  __shared__ __align__(16) _Float16 Bs[BN * BK];  // 16 KB

  int blk = blockIdx.x;
  int xcd = blk & 7, slot = blk >> 3;
  int xt = slot >> 3, ys = slot & 7;    // x-major within XCD
  int yt = (xcd << 3) | ys;             // y-stripe per XCD
  int m0 = yt * BM, n0 = xt * BN;

  int tid = threadIdx.x, wid = tid >> 6, lane = tid & 63;
  int srow = lane >> 3;                       // staging row within 8
  int sgk = ((lane & 7) ^ (srow & 7)) * 8;    // XOR-permuted global k-chunk
  int wm = (wid >> 1) * 64, wn = (wid & 1) * 64;
  int fm = lane & 15, fc = lane >> 4;         // frag: m/n = lane&15, k-chunk = lane>>4

  f32x4 acc[4][4] = {};

  for (int kt = 0; kt < Kd / BK; ++kt) {
    if (kt) __syncthreads();                 // protect LDS before overwrite
    int kk = kt * BK;
    int r0 = wid * 32;                       // each wave stages 32 rows of A and of B
#pragma unroll
    for (int i = 0; i < 4; ++i) {
      gl_lds16(A  + (size_t)(m0 + r0 + i * 8 + srow) * Kd + kk + sgk, &As[(r0 + i * 8) * BK]);
      gl_lds16(Bt + (size_t)(n0 + r0 + i * 8 + srow) * Kd + kk + sgk, &Bs[(r0 + i * 8) * BK]);
    }
    __syncthreads();                         // waits vmcnt(0): staging complete

#pragma unroll
    for (int ks = 0; ks < 2; ++ks) {         // two k=32 halves per tile
      h8v af[4], bfr[4];
#pragma unroll
      for (int i = 0; i < 4; ++i) {
        int row = wm + i * 16 + fm;
        af[i] = *(const h8v*)&As[row * BK + (((ks * 4 + fc) ^ (row & 7)) * 8)];
      }
#pragma unroll
      for (int j = 0; j < 4; ++j) {
        int row = wn + j * 16 + fm;
        bfr[j] = *(const h8v*)&Bs[row * BK + (((ks * 4 + fc) ^ (row & 7)) * 8)];
      }
#pragma unroll
      for (int i = 0; i < 4; ++i)
#pragma unroll
        for (int j = 0; j < 4; ++j)
          acc[i][j] = __builtin_amdgcn_mfma_f32_16x16x32_f16(af[i], bfr[j], acc[i][j], 0, 0, 0);
    }
  }

  // Output select: which 1024-wide matrix this n-tile belongs to (QKV fusion).
  int which = n0 >> 10, nc = n0 & 1023;
  _Float16* Cv = which == 0 ? C0 : (which == 1 ? C1 : C2);

  // C/D layout (m89-verified, dtype-independent): col = lane&15, row = (lane>>4)*4 + reg
  int rr = (lane >> 4) * 4, cc = lane & 15;
#pragma unroll
  for (int i = 0; i < 4; ++i)
#pragma unroll
    for (int j = 0; j < 4; ++j) {
      size_t base = (size_t)(m0 + wm + i * 16 + rr) * DM + (nc + wn + j * 16 + cc);
#pragma unroll
      for (int r = 0; r < 4; ++r)
        Cv[base + (size_t)r * DM] = (_Float16)acc[i][j][r];
    }
}

// ------- Wo GEMM: 128x64 tile -> 1024 blocks = 4 blocks/CU (16 waves/CU) ----
// Wo was 512 blocks = 8 waves/CU: latency-starved. fp32 output to d_out.
__global__ __launch_bounds__(256) void sda_gemm_wo_kernel(
    const _Float16* __restrict__ A, const _Float16* __restrict__ Bt,
    float* __restrict__ C) {
  constexpr int Kd = DM, BN2 = 64;
  __shared__ __align__(16) _Float16 As[BM * BK];   // 16 KB
  __shared__ __align__(16) _Float16 Bs[BN2 * BK];  //  8 KB

  int blk = blockIdx.x;
  int xcd = blk & 7, slot = blk >> 3;   // 128 slots/XCD
  int xt = slot >> 3, ys = slot & 7;    // 16 x-tiles, x-major
  int yt = (xcd << 3) | ys;
  int m0 = yt * BM, n0 = xt * BN2;

  int tid = threadIdx.x, wid = tid >> 6, lane = tid & 63;
  int srow = lane >> 3;
  int sgk = ((lane & 7) ^ (srow & 7)) * 8;
  int wm = (wid >> 1) * 64, wn = (wid & 1) * 32;
  int fm = lane & 15, fc = lane >> 4;

  f32x4 acc[4][2] = {};

  for (int kt = 0; kt < Kd / BK; ++kt) {
    if (kt) __syncthreads();
    int kk = kt * BK;
#pragma unroll
    for (int i = 0; i < 4; ++i)    // A: 128 rows, wave stages 32
      gl_lds16(A + (size_t)(m0 + wid * 32 + i * 8 + srow) * Kd + kk + sgk,
               &As[(wid * 32 + i * 8) * BK]);
#pragma unroll
    for (int i = 0; i < 2; ++i)    // B: 64 rows, wave stages 16
      gl_lds16(Bt + (size_t)(n0 + wid * 16 + i * 8 + srow) * Kd + kk + sgk,
               &Bs[(wid * 16 + i * 8) * BK]);
    __syncthreads();

#pragma unroll
    for (int ks = 0; ks < 2; ++ks) {
      h8v af[4], bfr[2];
#pragma unroll
      for (int i = 0; i < 4; ++i) {
        int row = wm + i * 16 + fm;
        af[i] = *(const h8v*)&As[row * BK + (((ks * 4 + fc) ^ (row & 7)) * 8)];
      }
#pragma unroll
      for (int j = 0; j < 2; ++j) {
        int row = wn + j * 16 + fm;
        bfr[j] = *(const h8v*)&Bs[row * BK + (((ks * 4 + fc) ^ (row & 7)) * 8)];
      }
#pragma unroll
      for (int i = 0; i < 4; ++i)
#pragma unroll
        for (int j = 0; j < 2; ++j)
          acc[i][j] = __builtin_amdgcn_mfma_f32_16x16x32_f16(af[i], bfr[j], acc[i][j], 0, 0, 0);
    }
  }

  int rr = (lane >> 4) * 4, cc = lane & 15;
#pragma unroll
  for (int i = 0; i < 4; ++i)
#pragma unroll
    for (int j = 0; j < 2; ++j) {
      size_t base = (size_t)(m0 + wm + i * 16 + rr) * DM + (n0 + wn + j * 16 + cc);
#pragma unroll
      for (int r = 0; r < 4; ++r)
        C[base + (size_t)r * DM] = acc[i][j][r];
    }
}

// ---------------- MFMA windowed attention (V transposed in LDS) ----------------
// Grid (S/64, B*H). Block = 256 = 4 waves; wave w owns q-rows [16w,16w+16).
// Q fragments load straight from global (no qs staging).
// V staged TRANSPOSED: vst[dim][k] stride 104 -> PV B-frag = one ds_read_b128
// per (step,tile) instead of 8 ds_read_u16 (R6 hot spot: 96 u16/lane).
__global__ __launch_bounds__(256) void sda_attn_kernel(
    const _Float16* __restrict__ Q, const _Float16* __restrict__ K,
    const _Float16* __restrict__ V, _Float16* __restrict__ O) {
  constexpr int VTS = 104; // vst k-stride (f16): 16B-aligned rows, reads 2-way max
  __shared__ __align__(16) _Float16 ks[80 * 64];      // 10 KB (rows 72..79 zero)
  __shared__ __align__(16) _Float16 vst[64 * VTS];    // 13 KB [dim][k], k 72..95 zero
  __shared__ __align__(16) float    scb[4 * 16 * 33]; //  8.25 KB per-wave scores
  __shared__ __align__(16) _Float16 wts[64 * 96];     // 12 KB softmax weights (banded)

  int bh = blockIdx.y, b = bh >> 4, h = bh & 15;
  int s0 = blockIdx.x * 64;
  int tid = threadIdx.x;
  size_t headoff = (size_t)b * S_LEN * DM + h * 64;

  int wid = tid >> 6, lane = tid & 63;
  int fm = lane & 15, fkg = (lane >> 4) * 8;
  int rr = (lane >> 4) * 4, cc = lane & 15;

  // Q fragment straight from global (rows always valid).
  const _Float16* qrow = Q + headoff + (size_t)(s0 + wid * 16 + fm) * DM;
  h8v aq0 = *(const h8v*)(qrow + fkg);
  h8v aq1 = *(const h8v*)(qrow + 32 + fkg);

  // ---- stage K (row-major) ----
  for (int idx = tid; idx < 72 * 8; idx += 256) {
    int row = idx >> 3, ch = (idx & 7) * 8;
    int pos = s0 - RAD + row;
    uint4 kv = make_uint4(0, 0, 0, 0);
    if (pos >= 0) kv = *(const uint4*)(K + headoff + (size_t)pos * DM + ch);
    *(uint4*)&ks[row * 64 + ch] = kv;
  }
  // ---- stage V transposed: lanes span rows (write ~2-way, free) ----
  for (int idx = tid; idx < 72 * 8; idx += 256) {
    int row = idx % 72, chb = (idx / 72) * 8;
    int pos = s0 - RAD + row;
    uint4 vv = make_uint4(0, 0, 0, 0);
    if (pos >= 0) vv = *(const uint4*)(V + headoff + (size_t)pos * DM + chb);
    union { uint4 v; _Float16 hh[8]; } u; u.v = vv;
#pragma unroll
    for (int d = 0; d < 8; ++d) vst[(chb + d) * VTS + row] = u.hh[d];
  }
  if (tid < 64)                                          // ks rows 72..79 -> 0
    *(uint4*)&ks[(72 + (tid >> 3)) * 64 + (tid & 7) * 8] = make_uint4(0, 0, 0, 0);
  for (int idx = tid; idx < 64 * 6; idx += 256) {        // vst k 72..95 -> 0
    int dim = idx / 6, p = idx % 6;
    *(uint2*)&vst[dim * VTS + 72 + p * 4] = make_uint2(0, 0);
  }
  for (int idx = tid; idx < 768; idx += 256)             // wts -> 0 (12 KB)
    ((uint4*)wts)[idx] = make_uint4(0, 0, 0, 0);
  __syncthreads();

  // ---- QK^T: wave w -> m-tile w (16 rows) x n-tiles {w, w+1} x K=64 ----
  {
    f32x4 accs[2] = {};
#pragma unroll
    for (int ti = 0; ti < 2; ++ti) {
      int t = wid + ti;
      h8v bk0 = *(const h8v*)&ks[(t * 16 + fm) * 64 + fkg];
      h8v bk1 = *(const h8v*)&ks[(t * 16 + fm) * 64 + 32 + fkg];
      accs[ti] = __builtin_amdgcn_mfma_f32_16x16x32_f16(aq0, bk0, accs[ti], 0, 0, 0);
      accs[ti] = __builtin_amdgcn_mfma_f32_16x16x32_f16(aq1, bk1, accs[ti], 0, 0, 0);
    }
#pragma unroll
    for (int ti = 0; ti < 2; ++ti)
#pragma unroll
      for (int r = 0; r < 4; ++r)
        scb[wid * 528 + (rr + r) * 33 + ti * 16 + cc] = accs[ti][r];
  }
  __syncthreads();

  // ---- softmax on the 9-wide band: thread r owns q-row r ----
  // global score-col of (q-row r, j) = r + j; local col in wave (r>>4)'s
  // buffer = (r&15) + j  (max 15+8=23 < 32).
  if (tid < 64) {
    int r = tid, s = s0 + r;
    const float* my = &scb[(r >> 4) * 528 + (r & 15) * 33 + (r & 15)];
    float e[9], mx = -1e30f;
#pragma unroll
    for (int j = 0; j < 9; ++j) {
      float p = my[j] * INV2T;
      e[j] = (s - RAD + j >= 0) ? p : -1e30f;
      mx = fmaxf(mx, e[j]);
    }
    float se = 0.f;
#pragma unroll
    for (int j = 0; j < 9; ++j) { e[j] = __expf(e[j] - mx); se += e[j]; }
    float inv = 1.f / se;
#pragma unroll
    for (int j = 0; j < 9; ++j)
      wts[r * 96 + r + j] = (_Float16)(e[j] * inv);
  }
  __syncthreads();

  // ---- PV: O(64x64) = W(64x96) @ V(96x64); 3 k-steps, b128 V reads ----
  f32x4 acco[4] = {};
#pragma unroll
  for (int step = 0; step < 3; ++step) {
    h8v aw = *(const h8v*)&wts[(wid * 16 + fm) * 96 + step * 32 + fkg];
    int kb = step * 32 + fkg;
#pragma unroll
    for (int t = 0; t < 4; ++t) {
      h8v bv = *(const h8v*)&vst[(t * 16 + fm) * VTS + kb];  // B[k][n] contiguous in k
      acco[t] = __builtin_amdgcn_mfma_f32_16x16x32_f16(aw, bv, acco[t], 0, 0, 0);
    }
  }
#pragma unroll
  for (int t = 0; t < 4; ++t)
#pragma unroll
    for (int r = 0; r < 4; ++r)
      O[headoff + (size_t)(s0 + wid * 16 + rr + r) * DM + t * 16 + cc] =
          (_Float16)acco[t][r];
}

extern "C" void kernel_launch(void* const* d_in, const int* in_sizes, int n_in,
                              void* d_out, int out_size, void* d_ws, size_t ws_size,
                              hipStream_t stream) {
  (void)in_sizes; (void)n_in; (void)out_size; (void)ws_size;
  const float* x  = (const float*)d_in[0];
  const float* Wq = (const float*)d_in[1];
  const float* Wk = (const float*)d_in[2];
  const float* Wv = (const float*)d_in[3];
  const float* Wo = (const float*)d_in[4];

  char* ws = (char*)d_ws;
  const size_t MB = 1ull << 20;
  _Float16* xh    = (_Float16*)(ws + 0);        // 16 MB
  _Float16* WqkvT = (_Float16*)(ws + 16 * MB);  // 6 MB: Wq^T|Wk^T|Wv^T rows 0..3071
  _Float16* WoT   = (_Float16*)(ws + 22 * MB);  // 2 MB
  _Float16* Qh    = (_Float16*)(ws + 24 * MB);  // 16 MB each
  _Float16* Kh    = (_Float16*)(ws + 40 * MB);
  _Float16* Vh    = (_Float16*)(ws + 56 * MB);
  _Float16* Ah    = (_Float16*)(ws + 72 * MB);  // total 88 MB

  sda_prep_kernel<<<dim3(32, 32, 8), dim3(32, 8), 0, stream>>>(
      x, xh, Wq, Wk, Wv, Wo,
      WqkvT, WqkvT + (size_t)DM * DM, WqkvT + 2ull * DM * DM, WoT);

  // QKV fused: M=8192, N=3072 -> 24 x-tiles * 64 y-tiles = 1536 blocks (1D, swizzled)
  sda_gemm_swz_kernel<<<1536, 256, 0, stream>>>(xh, WqkvT, Qh, Kh, Vh);
  sda_attn_kernel<<<dim3(64, 32), 256, 0, stream>>>(Qh, Kh, Vh, Ah);
  // Wo: 128x64 tile -> 16 x-tiles * 64 y-tiles = 1024 blocks (4/CU)
  sda_gemm_wo_kernel<<<1024, 256, 0, stream>>>(Ah, WoT, (float*)d_out);
}

// Round 8
// 184.979 us; speedup vs baseline: 1.9894x; 1.0266x over previous
//
#include <hip/hip_runtime.h>
#include <stdint.h>

// Problem constants (from reference): B=2, S=4096, D_MODEL=1024, H=16, d_k=64
// RADIUS = ceil(sqrt(4*0.28*ln(1e6))*2) = 8, window = 9 (positions s-8..s)
constexpr int S_LEN = 4096;
constexpr int DM    = 1024;
constexpr int RAD   = 8;
constexpr float INV2T = 1.7857142857142858f; // 1/(2*0.28)

constexpr int BM = 128, BN = 128, BK = 64;   // BK=64: 32 MFMA/barrier (measured: 31.5->38% MfmaUtil)

typedef _Float16 h8v __attribute__((ext_vector_type(8)));  // 8 f16 (4 VGPRs) MFMA frag
typedef float f32x4  __attribute__((ext_vector_type(4)));  // MFMA accumulator

// async global->LDS, 16B/lane. LDS dst is wave-uniform base + lane*16 (HW rule).
static __device__ __forceinline__ void gl_lds16(const void* gp, void* lp) {
  auto g = (const __attribute__((address_space(1))) void*)(uintptr_t)gp;
  auto l = (__attribute__((address_space(3))) void*)(uint32_t)(uintptr_t)lp;
  __builtin_amdgcn_global_load_lds(g, l, 16, 0, 0);
}

// ---------------- prep: x->fp16 cast + 4x W transpose-cast, one launch -------
__global__ __launch_bounds__(256) void sda_prep_kernel(
    const float* __restrict__ X, _Float16* __restrict__ XH,
    const float* __restrict__ W0, const float* __restrict__ W1,
    const float* __restrict__ W2, const float* __restrict__ W3,
    _Float16* __restrict__ T0, _Float16* __restrict__ T1,
    _Float16* __restrict__ T2, _Float16* __restrict__ T3) {
  __shared__ float t[32][33];
  int z = blockIdx.z;
  int tx = threadIdx.x, ty = threadIdx.y;
  if (z < 4) {
    const float* W = z == 0 ? W0 : (z == 1 ? W1 : (z == 2 ? W2 : W3));
    _Float16*    T = z == 0 ? T0 : (z == 1 ? T1 : (z == 2 ? T2 : T3));
    int n0 = blockIdx.x * 32, k0 = blockIdx.y * 32;
#pragma unroll
    for (int i = 0; i < 4; ++i)
      t[ty + 8 * i][tx] = W[(size_t)(k0 + ty + 8 * i) * DM + n0 + tx];
    __syncthreads();
#pragma unroll
    for (int i = 0; i < 4; ++i)
      T[(size_t)(n0 + ty + 8 * i) * DM + k0 + tx] = (_Float16)t[tx][ty + 8 * i];
  } else {
    int blk = (z - 4) * 1024 + blockIdx.y * 32 + blockIdx.x;
    int i = blk * 256 + ty * 32 + tx;
    const float4* x4 = (const float4*)X;
    float4 a = x4[2 * i], b = x4[2 * i + 1];
    float f[8] = {a.x, a.y, a.z, a.w, b.x, b.y, b.z, b.w};
    union { _Float16 h[8]; uint4 v; } o;
#pragma unroll
    for (int j = 0; j < 8; ++j) o.h[j] = (_Float16)f[j];
    ((uint4*)XH)[i] = o.v;
  }
}

// ------- fp16 GEMM, XCD-swizzled, BK=64 (R6-verified: MfmaUtil 38%, conflicts 0) ----
__global__ __launch_bounds__(256) void sda_gemm_qkv_kernel(
    const _Float16* __restrict__ A, const _Float16* __restrict__ Bt,
    _Float16* __restrict__ C0, _Float16* __restrict__ C1,
    _Float16* __restrict__ C2) {
  constexpr int Kd = DM;
  __shared__ __align__(16) _Float16 As[BM * BK];  // 16 KB, 128B rows, chunk-XORed
  __shared__ __align__(16) _Float16 Bs[BN * BK];  // 16 KB

  int blk = blockIdx.x;
  int xcd = blk & 7, slot = blk >> 3;
  int xt = slot >> 3, ys = slot & 7;    // x-major within XCD
  int yt = (xcd << 3) | ys;             // y-stripe per XCD
  int m0 = yt * BM, n0 = xt * BN;

  int tid = threadIdx.x, wid = tid >> 6, lane = tid & 63;
  int srow = lane >> 3;
  int sgk = ((lane & 7) ^ (srow & 7)) * 8;    // XOR-permuted global k-chunk
  int wm = (wid >> 1) * 64, wn = (wid & 1) * 64;
  int fm = lane & 15, fc = lane >> 4;

  f32x4 acc[4][4] = {};

  for (int kt = 0; kt < Kd / BK; ++kt) {
    if (kt) __syncthreads();
    int kk = kt * BK;
    int r0 = wid * 32;
#pragma unroll
    for (int i = 0; i < 4; ++i) {
      gl_lds16(A  + (size_t)(m0 + r0 + i * 8 + srow) * Kd + kk + sgk, &As[(r0 + i * 8) * BK]);
      gl_lds16(Bt + (size_t)(n0 + r0 + i * 8 + srow) * Kd + kk + sgk, &Bs[(r0 + i * 8) * BK]);
    }
    __syncthreads();

#pragma unroll
    for (int ks = 0; ks < 2; ++ks) {
      h8v af[4], bfr[4];
#pragma unroll
      for (int i = 0; i < 4; ++i) {
        int row = wm + i * 16 + fm;
        af[i] = *(const h8v*)&As[row * BK + (((ks * 4 + fc) ^ (row & 7)) * 8)];
      }
#pragma unroll
      for (int j = 0; j < 4; ++j) {
        int row = wn + j * 16 + fm;
        bfr[j] = *(const h8v*)&Bs[row * BK + (((ks * 4 + fc) ^ (row & 7)) * 8)];
      }
#pragma unroll
      for (int i = 0; i < 4; ++i)
#pragma unroll
        for (int j = 0; j < 4; ++j)
          acc[i][j] = __builtin_amdgcn_mfma_f32_16x16x32_f16(af[i], bfr[j], acc[i][j], 0, 0, 0);
    }
  }

  int which = n0 >> 10, nc = n0 & 1023;
  _Float16* Cv = which == 0 ? C0 : (which == 1 ? C1 : C2);

  int rr = (lane >> 4) * 4, cc = lane & 15;
#pragma unroll
  for (int i = 0; i < 4; ++i)
#pragma unroll
    for (int j = 0; j < 4; ++j) {
      size_t base = (size_t)(m0 + wm + i * 16 + rr) * DM + (nc + wn + j * 16 + cc);
#pragma unroll
      for (int r = 0; r < 4; ++r)
        Cv[base + (size_t)r * DM] = (_Float16)acc[i][j][r];
    }
}

// ------- Wo GEMM: REVERT to 128x128 (R7's 128x64 halved MFMA/barrier density) ----
__global__ __launch_bounds__(256) void sda_gemm_wo_kernel(
    const _Float16* __restrict__ A, const _Float16* __restrict__ Bt,
    float* __restrict__ C) {
  constexpr int Kd = DM;
  __shared__ __align__(16) _Float16 As[BM * BK];
  __shared__ __align__(16) _Float16 Bs[BN * BK];

  int blk = blockIdx.x;
  int xcd = blk & 7, slot = blk >> 3;   // 64 slots/XCD
  int xt = slot >> 3, ys = slot & 7;    // 8 x-tiles, x-major
  int yt = (xcd << 3) | ys;
  int m0 = yt * BM, n0 = xt * BN;

  int tid = threadIdx.x, wid = tid >> 6, lane = tid & 63;
  int srow = lane >> 3;
  int sgk = ((lane & 7) ^ (srow & 7)) * 8;
  int wm = (wid >> 1) * 64, wn = (wid & 1) * 64;
  int fm = lane & 15, fc = lane >> 4;

  f32x4 acc[4][4] = {};

  for (int kt = 0; kt < Kd / BK; ++kt) {
    if (kt) __syncthreads();
    int kk = kt * BK;
    int r0 = wid * 32;
#pragma unroll
    for (int i = 0; i < 4; ++i) {
      gl_lds16(A  + (size_t)(m0 + r0 + i * 8 + srow) * Kd + kk + sgk, &As[(r0 + i * 8) * BK]);
      gl_lds16(Bt + (size_t)(n0 + r0 + i * 8 + srow) * Kd + kk + sgk, &Bs[(r0 + i * 8) * BK]);
    }
    __syncthreads();

#pragma unroll
    for (int ks = 0; ks < 2; ++ks) {
      h8v af[4], bfr[4];
#pragma unroll
      for (int i = 0; i < 4; ++i) {
        int row = wm + i * 16 + fm;
        af[i] = *(const h8v*)&As[row * BK + (((ks * 4 + fc) ^ (row & 7)) * 8)];
      }
#pragma unroll
      for (int j = 0; j < 4; ++j) {
        int row = wn + j * 16 + fm;
        bfr[j] = *(const h8v*)&Bs[row * BK + (((ks * 4 + fc) ^ (row & 7)) * 8)];
      }
#pragma unroll
      for (int i = 0; i < 4; ++i)
#pragma unroll
        for (int j = 0; j < 4; ++j)
          acc[i][j] = __builtin_amdgcn_mfma_f32_16x16x32_f16(af[i], bfr[j], acc[i][j], 0, 0, 0);
    }
  }

  int rr = (lane >> 4) * 4, cc = lane & 15;
#pragma unroll
  for (int i = 0; i < 4; ++i)
#pragma unroll
    for (int j = 0; j < 4; ++j) {
      size_t base = (size_t)(m0 + wm + i * 16 + rr) * DM + (n0 + wn + j * 16 + cc);
#pragma unroll
      for (int r = 0; r < 4; ++r)
        C[base + (size_t)r * DM] = acc[i][j][r];
    }
}

// ---------------- BARRIER-FREE per-wave windowed attention ----------------
// Grid (S/64, B*H), 256 thr = 4 waves. Wave w owns q-rows [16w,16w+16) and
// needs ONLY K/V pos [s0+16w-8, s0+16w+15] (24 rows) -> per-wave LDS slices,
// ZERO __syncthreads (in-wave DS ordering via lgkmcnt only, per ISA wave-
// reduce pattern). Strides are odd-dword multiples (kw 144B, vt/wt 80B,
// sc 132B) -> <=2-way bank aliasing (free, m136); kills the 128B-stride
// 16-way b128 collisions present in R4-R7.
// QK: 4 MFMAs (2 key-tiles x K=64; kw rows 24-31 garbage -> only unused
// score cols). PV: 4 MFMAs (single K=32 covers the zero-padded band; vt
// cols 24-31 zeroed to avoid 0*NaN).
__global__ __launch_bounds__(256) void sda_attn_kernel(
    const _Float16* __restrict__ Q, const _Float16* __restrict__ K,
    const _Float16* __restrict__ V, _Float16* __restrict__ O) {
  constexpr int KS  = 72;  // kw row stride f16: 144B = 36 dw
  constexpr int VTS = 40;  // vt row stride f16: 80B = 20 dw
  constexpr int WS  = 40;  // wt row stride f16
  __shared__ __align__(16) _Float16 kw[4][32 * KS];   // 4.5 KB/wave
  __shared__ __align__(16) _Float16 vt[4][64 * VTS];  // 5 KB/wave [dim][key]
  __shared__ __align__(16) float    sc[4][16 * 33];   // 2.06 KB/wave
  __shared__ __align__(16) _Float16 wt[4][16 * WS];   // 1.25 KB/wave => 52.5 KB total

  int bh = blockIdx.y, b = bh >> 4, h = bh & 15;
  int s0 = blockIdx.x * 64;
  int tid = threadIdx.x, wid = tid >> 6, lane = tid & 63;
  size_t headoff = (size_t)b * S_LEN * DM + h * 64;

  _Float16* kwp = kw[wid];
  _Float16* vtp = vt[wid];
  float*    scp = sc[wid];
  _Float16* wtp = wt[wid];

  int p0 = s0 + wid * 16 - RAD;    // first key pos of this wave's 24-key band
  int fm = lane & 15, fkg = (lane >> 4) * 8;
  int rr = (lane >> 4) * 4, cc = lane & 15;

  // zero wt fully (1280 B = 80 x 16B) and vt key-cols 24..31 (0*NaN guard)
  {
    uint4 z = make_uint4(0, 0, 0, 0);
    ((uint4*)wtp)[lane] = z;
    if (lane < 16) ((uint4*)wtp)[64 + lane] = z;
    *(uint4*)&vtp[lane * VTS + 24] = z;
  }

  // stage K rows 0..23 row-major (24 x 8 chunks = 192 items, 3/lane)
#pragma unroll
  for (int i = 0; i < 3; ++i) {
    int item = i * 64 + lane;
    int row = item >> 3, ch = (item & 7) * 8;
    int pos = p0 + row;
    uint4 kv = make_uint4(0, 0, 0, 0);
    if (pos >= 0) kv = *(const uint4*)(K + headoff + (size_t)pos * DM + ch);
    *(uint4*)&kwp[row * KS + ch] = kv;
  }
  // stage V transposed: vt[dim][key]
#pragma unroll
  for (int i = 0; i < 3; ++i) {
    int item = i * 64 + lane;
    int row = item >> 3, chb = (item & 7) * 8;
    int pos = p0 + row;
    uint4 vv = make_uint4(0, 0, 0, 0);
    if (pos >= 0) vv = *(const uint4*)(V + headoff + (size_t)pos * DM + chb);
    union { uint4 v; _Float16 hh[8]; } u; u.v = vv;
#pragma unroll
    for (int d = 0; d < 8; ++d) vtp[(chb + d) * VTS + row] = u.hh[d];
  }

  // Q fragments straight from global (rows always valid)
  const _Float16* qrow = Q + headoff + (size_t)(s0 + wid * 16 + fm) * DM;
  h8v aq0 = *(const h8v*)(qrow + fkg);
  h8v aq1 = *(const h8v*)(qrow + 32 + fkg);

  // ---- QK^T: 2 local key-tiles x K=64 ----
  f32x4 accs[2] = {};
#pragma unroll
  for (int t = 0; t < 2; ++t) {
    h8v bk0 = *(const h8v*)&kwp[(t * 16 + fm) * KS + fkg];
    h8v bk1 = *(const h8v*)&kwp[(t * 16 + fm) * KS + 32 + fkg];
    accs[t] = __builtin_amdgcn_mfma_f32_16x16x32_f16(aq0, bk0, accs[t], 0, 0, 0);
    accs[t] = __builtin_amdgcn_mfma_f32_16x16x32_f16(aq1, bk1, accs[t], 0, 0, 0);
  }
#pragma unroll
  for (int t = 0; t < 2; ++t)
#pragma unroll
    for (int r = 0; r < 4; ++r)
      scp[(rr + r) * 33 + t * 16 + cc] = accs[t][r];

  // ---- softmax: lane r (0..15) owns q-row r; band cols r..r+8 (< 24) ----
  if (lane < 16) {
    int r = lane, s = s0 + wid * 16 + r;
    const float* my = &scp[r * 33 + r];
    float e[9], mx = -1e30f;
#pragma unroll
    for (int j = 0; j < 9; ++j) {
      float p = my[j] * INV2T;
      e[j] = (s - RAD + j >= 0) ? p : -1e30f;
      mx = fmaxf(mx, e[j]);
    }
    float se = 0.f;
#pragma unroll
    for (int j = 0; j < 9; ++j) { e[j] = __expf(e[j] - mx); se += e[j]; }
    float inv = 1.f / se;
#pragma unroll
    for (int j = 0; j < 9; ++j)
      wtp[r * WS + r + j] = (_Float16)(e[j] * inv);
  }

  // ---- PV: O(16x64) = wt(16x32) @ V(32x64); one K=32 MFMA per n-tile ----
  f32x4 acco[4] = {};
  h8v aw = *(const h8v*)&wtp[fm * WS + fkg];
#pragma unroll
  for (int t = 0; t < 4; ++t) {
    h8v bv = *(const h8v*)&vtp[(t * 16 + fm) * VTS + fkg];
    acco[t] = __builtin_amdgcn_mfma_f32_16x16x32_f16(aw, bv, acco[t], 0, 0, 0);
  }
#pragma unroll
  for (int t = 0; t < 4; ++t)
#pragma unroll
    for (int r = 0; r < 4; ++r)
      O[headoff + (size_t)(s0 + wid * 16 + rr + r) * DM + t * 16 + cc] =
          (_Float16)acco[t][r];
}

extern "C" void kernel_launch(void* const* d_in, const int* in_sizes, int n_in,
                              void* d_out, int out_size, void* d_ws, size_t ws_size,
                              hipStream_t stream) {
  (void)in_sizes; (void)n_in; (void)out_size; (void)ws_size;
  const float* x  = (const float*)d_in[0];
  const float* Wq = (const float*)d_in[1];
  const float* Wk = (const float*)d_in[2];
  const float* Wv = (const float*)d_in[3];
  const float* Wo = (const float*)d_in[4];

  char* ws = (char*)d_ws;
  const size_t MB = 1ull << 20;
  _Float16* xh    = (_Float16*)(ws + 0);        // 16 MB
  _Float16* WqkvT = (_Float16*)(ws + 16 * MB);  // 6 MB: Wq^T|Wk^T|Wv^T
  _Float16* WoT   = (_Float16*)(ws + 22 * MB);  // 2 MB
  _Float16* Qh    = (_Float16*)(ws + 24 * MB);  // 16 MB each
  _Float16* Kh    = (_Float16*)(ws + 40 * MB);
  _Float16* Vh    = (_Float16*)(ws + 56 * MB);
  _Float16* Ah    = (_Float16*)(ws + 72 * MB);  // total 88 MB

  sda_prep_kernel<<<dim3(32, 32, 8), dim3(32, 8), 0, stream>>>(
      x, xh, Wq, Wk, Wv, Wo,
      WqkvT, WqkvT + (size_t)DM * DM, WqkvT + 2ull * DM * DM, WoT);

  // QKV fused: M=8192, N=3072 -> 1536 blocks (1D, XCD-swizzled)
  sda_gemm_qkv_kernel<<<1536, 256, 0, stream>>>(xh, WqkvT, Qh, Kh, Vh);
  sda_attn_kernel<<<dim3(64, 32), 256, 0, stream>>>(Qh, Kh, Vh, Ah);
  // Wo: 128x128 -> 512 blocks
  sda_gemm_wo_kernel<<<512, 256, 0, stream>>>(Ah, WoT, (float*)d_out);
}